// Round 2
// baseline (529.055 us; speedup 1.0000x reference)
//
#include <hip/hip_runtime.h>
#include <cstdint>

static constexpr int N = 20000;
static constexpr int E = 320000;
static constexpr int R = 8;
static constexpr int H = 4;
static constexpr int C = 256;

using short8 = __attribute__((ext_vector_type(8))) short;
using f32x4  = __attribute__((ext_vector_type(4))) float;

__device__ __forceinline__ float lrelu(float x, float s) { return x >= 0.f ? x : s * x; }
__device__ __forceinline__ unsigned short f2bf(float f) {
    unsigned u = __float_as_uint(f);
    unsigned r = (u + 0x7FFFu + ((u >> 16) & 1u)) >> 16;
    return (unsigned short)r;
}
__device__ __forceinline__ float bf2f(unsigned short s) {
    return __uint_as_float(((unsigned)s) << 16);
}

// async global->LDS DMA, 16B per lane; LDS dest is wave-uniform base + lane*16
__device__ __forceinline__ void gl2l16(const unsigned short* g, unsigned short* l) {
    __builtin_amdgcn_global_load_lds(
        (const __attribute__((address_space(1))) unsigned int*)g,
        (__attribute__((address_space(3))) unsigned int*)l, 16, 0, 0);
}

// ---------------- CSR build ----------------
__global__ void k_zero_int(int* p, int n) {
    int i = blockIdx.x * blockDim.x + threadIdx.x;
    if (i < n) p[i] = 0;
}

__global__ void k_count(const int* __restrict__ ei, int* __restrict__ cnt) {
    int e = blockIdx.x * blockDim.x + threadIdx.x;
    if (e < E) atomicAdd(&cnt[ei[E + e]], 1);
}

// exclusive scan of cnt -> rowptr; also emits cursor copy and dis = rsqrt(cnt+1)
__global__ __launch_bounds__(1024) void k_scan(const int* __restrict__ cnt,
                                               int* __restrict__ rowptr,
                                               int* __restrict__ cursor,
                                               float* __restrict__ dis) {
    __shared__ int part[1024];
    const int CH = (N + 1023) / 1024;  // 20
    int t = threadIdx.x;
    int base = t * CH;
    int sum = 0;
    for (int j = 0; j < CH; ++j) {
        int idx = base + j;
        if (idx < N) sum += cnt[idx];
    }
    part[t] = sum;
    __syncthreads();
    for (int off = 1; off < 1024; off <<= 1) {
        int v = 0;
        if (t >= off) v = part[t - off];
        __syncthreads();
        if (t >= off) part[t] += v;
        __syncthreads();
    }
    int run = part[t] - sum;
    for (int j = 0; j < CH; ++j) {
        int idx = base + j;
        if (idx < N) {
            int cv = cnt[idx];
            rowptr[idx] = run;
            cursor[idx] = run;
            dis[idx] = rsqrtf((float)cv + 1.0f);
            run += cv;
        }
    }
    if (t == 1023) rowptr[N] = part[1023];
}

// csr_se packs (edge_type<<16)|src ; csr_eid keeps original edge id
__global__ void k_scatter(const int* __restrict__ ei, const int* __restrict__ et,
                          int* __restrict__ cursor, int* __restrict__ csr_se,
                          int* __restrict__ csr_eid) {
    int e = blockIdx.x * blockDim.x + threadIdx.x;
    if (e >= E) return;
    int d = ei[E + e];
    int pos = atomicAdd(&cursor[d], 1);
    csr_se[pos] = (et[e] << 16) | ei[e];
    csr_eid[pos] = e;
}

// ---------------- GCN ----------------
__global__ void k_h1(const float* __restrict__ x, const float* __restrict__ W,
                     float* __restrict__ h) {
    int idx = blockIdx.x * blockDim.x + threadIdx.x;
    if (idx >= N * 32) return;
    int n = idx >> 5, f = idx & 31;
    const float* xr = x + n * 4;
    float acc = 0.f;
#pragma unroll
    for (int c = 0; c < 4; ++c) acc += xr[c] * W[c * 32 + f];
    h[idx] = acc;
}

__global__ void k_agg32(const int* __restrict__ rowptr, const int* __restrict__ csr_se,
                        const float* __restrict__ dis, const float* __restrict__ h,
                        const float* __restrict__ b, float* __restrict__ c) {
    int idx = blockIdx.x * blockDim.x + threadIdx.x;
    if (idx >= N * 32) return;
    int d = idx >> 5, f = idx & 31;
    int beg = rowptr[d], end = rowptr[d + 1];
    float acc = 0.f;
    for (int i = beg; i < end; ++i) {
        int s = csr_se[i] & 0xFFFF;
        acc += dis[s] * h[s * 32 + f];
    }
    float dd = dis[d];
    c[idx] = dd * acc + dd * dd * h[idx] + b[f];
}

// h2 (bf16) + kg copy into x0/xb0, one dispatch
__global__ void k_h2kg(const float* __restrict__ c1, const float* __restrict__ W,
                       const float* __restrict__ kg, unsigned short* __restrict__ h,
                       float* __restrict__ x0, unsigned short* __restrict__ xb0) {
    int idx = blockIdx.x * blockDim.x + threadIdx.x;
    if (idx >= N * 128) return;
    int n = idx >> 7, f = idx & 127;
    const float* cr = c1 + n * 32;
    float acc = 0.f;
    for (int c = 0; c < 32; ++c) acc += lrelu(cr[c], 0.01f) * W[c * 128 + f];
    h[idx] = f2bf(acc);
    float v = kg[idx];
    x0[n * 256 + f] = v;
    xb0[n * 256 + f] = f2bf(v);
}

__global__ void k_agg128(const int* __restrict__ rowptr, const int* __restrict__ csr_se,
                         const float* __restrict__ dis,
                         const unsigned short* __restrict__ h,
                         const float* __restrict__ b, float* __restrict__ x0,
                         unsigned short* __restrict__ xb0) {
    int idx = blockIdx.x * blockDim.x + threadIdx.x;
    if (idx >= N * 128) return;
    int d = idx >> 7, f = idx & 127;
    int beg = rowptr[d], end = rowptr[d + 1];
    float acc = 0.f;
    int i = beg;
    for (; i + 2 <= end; i += 2) {
        int s0 = csr_se[i] & 0xFFFF;
        int s1 = csr_se[i + 1] & 0xFFFF;
        float d0 = dis[s0], d1 = dis[s1];
        float v0 = bf2f(h[s0 * 128 + f]), v1 = bf2f(h[s1 * 128 + f]);
        acc += d0 * v0 + d1 * v1;
    }
    if (i < end) {
        int s = csr_se[i] & 0xFFFF;
        acc += dis[s] * bf2f(h[s * 128 + f]);
    }
    float dd = dis[d];
    float v = dd * acc + dd * dd * bf2f(h[d * 128 + f]) + b[f];
    x0[d * 256 + 128 + f] = v;
    xb0[d * 256 + 128 + f] = f2bf(v);
}

// ---------------- RGAT attention ----------------
// wave-per-(r,i) W@q / W@k projection: coalesced row read + shuffle reduce.
// wqkb[n][k]: n<32 -> q proj (n = r*4+h), n>=32 -> k proj (n = 32+r*4+h)
__global__ __launch_bounds__(256) void k_wqkb(const float* __restrict__ W,
                                              const float* __restrict__ q,
                                              const float* __restrict__ kmat,
                                              unsigned short* __restrict__ wqkb) {
    int w = (blockIdx.x * blockDim.x + threadIdx.x) >> 6;  // 0..2047
    int lane = threadIdx.x & 63;
    int r = w >> 8, i = w & 255;
    const float* wr = W + ((size_t)(r * 256 + i)) * 256;
    float4 a = *(const float4*)(wr + lane * 4);
    float aq0 = 0.f, aq1 = 0.f, aq2 = 0.f, aq3 = 0.f;
    float ak0 = 0.f, ak1 = 0.f, ak2 = 0.f, ak3 = 0.f;
    int o = lane * 4;
    const float av[4] = {a.x, a.y, a.z, a.w};
#pragma unroll
    for (int j = 0; j < 4; ++j) {
        float4 qv = *(const float4*)(q + (o + j) * 4);
        float4 kv = *(const float4*)(kmat + (o + j) * 4);
        aq0 += av[j] * qv.x; aq1 += av[j] * qv.y;
        aq2 += av[j] * qv.z; aq3 += av[j] * qv.w;
        ak0 += av[j] * kv.x; ak1 += av[j] * kv.y;
        ak2 += av[j] * kv.z; ak3 += av[j] * kv.w;
    }
#pragma unroll
    for (int d = 1; d < 64; d <<= 1) {
        aq0 += __shfl_xor(aq0, d); aq1 += __shfl_xor(aq1, d);
        aq2 += __shfl_xor(aq2, d); aq3 += __shfl_xor(aq3, d);
        ak0 += __shfl_xor(ak0, d); ak1 += __shfl_xor(ak1, d);
        ak2 += __shfl_xor(ak2, d); ak3 += __shfl_xor(ak3, d);
    }
    if (lane == 0) {
        int nq = r * 4, nk = 32 + r * 4;
        wqkb[(nq + 0) * 256 + i] = f2bf(aq0);
        wqkb[(nq + 1) * 256 + i] = f2bf(aq1);
        wqkb[(nq + 2) * 256 + i] = f2bf(aq2);
        wqkb[(nq + 3) * 256 + i] = f2bf(aq3);
        wqkb[(nk + 0) * 256 + i] = f2bf(ak0);
        wqkb[(nk + 1) * 256 + i] = f2bf(ak1);
        wqkb[(nk + 2) * 256 + i] = f2bf(ak2);
        wqkb[(nk + 3) * 256 + i] = f2bf(ak3);
    }
}

// qn|kn = xb @ wqkb^T via MFMA.  Block: 256 thr = 4 waves, 64 rows per block.
#define QP 264
__global__ __launch_bounds__(256) void k_qnkn_mfma(
    const unsigned short* __restrict__ xb, const unsigned short* __restrict__ wqkb,
    float* __restrict__ qn, float* __restrict__ kn)
{
    __shared__ unsigned short Ws[64 * QP];
    int t = threadIdx.x;
    {
        int r = t >> 2, off = (t & 3) * 64;
#pragma unroll
        for (int i = 0; i < 8; ++i)
            *(uint4*)(&Ws[r * QP + off + i * 8]) =
                *(const uint4*)(wqkb + r * 256 + off + i * 8);
    }
    __syncthreads();
    int wave = t >> 6, lane = t & 63;
    int lrow = lane & 15, kq = lane >> 4;
    int mw = blockIdx.x * 64 + wave * 16;
    int gm = mw + lrow;
    int gmc = gm < N ? gm : N - 1;

    f32x4 acc[4];
#pragma unroll
    for (int j = 0; j < 4; ++j) acc[j] = (f32x4){0.f, 0.f, 0.f, 0.f};

    for (int k0 = 0; k0 < 8; ++k0) {
        short8 af = *(const short8*)(xb + (size_t)gmc * 256 + k0 * 32 + kq * 8);
#pragma unroll
        for (int j = 0; j < 4; ++j) {
            short8 bf4 = *(const short8*)(&Ws[(j * 16 + lrow) * QP + k0 * 32 + kq * 8]);
            acc[j] = __builtin_amdgcn_mfma_f32_16x16x32_bf16(af, bf4, acc[j], 0, 0, 0);
        }
    }
#pragma unroll
    for (int j = 0; j < 4; ++j) {
        int col = j * 16 + lrow;
#pragma unroll
        for (int reg = 0; reg < 4; ++reg) {
            int gr = mw + kq * 4 + reg;
            if (gr < N) {
                if (col < 32) qn[gr * 32 + col] = acc[j][reg];
                else          kn[gr * 32 + (col - 32)] = acc[j][reg];
            }
        }
    }
}

// wave-per-node softmax: lanes = 16 edge-slots x 4 heads, shuffle reductions.
__global__ void k_soft(const int* __restrict__ rowptr, const int* __restrict__ csr_se,
                       const int* __restrict__ csr_eid,
                       const float* __restrict__ qn, const float* __restrict__ kn,
                       float* __restrict__ alpha_csr, float* __restrict__ aout) {
    int wid = (blockIdx.x * blockDim.x + threadIdx.x) >> 6;
    int lane = threadIdx.x & 63;
    if (wid >= N) return;
    int d = wid;
    int beg = rowptr[d], end = rowptr[d + 1];
    if (beg >= end) return;
    int slot = lane >> 2, h = lane & 3;
    int nc = (end - beg + 15) >> 4;
    const float* qrow = qn + d * 32;

    auto rawv = [&](int i) {
        int se = csr_se[i];
        int tt = se >> 16, s = se & 0xFFFF;
        return lrelu(qrow[tt * 4 + h] + kn[s * 32 + tt * 4 + h], 0.2f);
    };

    float av[4];
    float m = -1e30f;
    for (int c = 0; c < nc; ++c) {
        int i = beg + c * 16 + slot;
        float v = (i < end) ? rawv(i) : -1e30f;
        if (c < 4) av[c] = v;
        m = fmaxf(m, v);
    }
    m = fmaxf(m, __shfl_xor(m, 4));
    m = fmaxf(m, __shfl_xor(m, 8));
    m = fmaxf(m, __shfl_xor(m, 16));
    m = fmaxf(m, __shfl_xor(m, 32));

    float sum = 0.f;
    for (int c = 0; c < nc; ++c) {
        int i = beg + c * 16 + slot;
        float ex = 0.f;
        if (i < end) {
            float v = (c < 4) ? av[c] : rawv(i);
            ex = expf(v - m);
        }
        if (c < 4) av[c] = ex;
        sum += ex;
    }
    sum += __shfl_xor(sum, 4);
    sum += __shfl_xor(sum, 8);
    sum += __shfl_xor(sum, 16);
    sum += __shfl_xor(sum, 32);
    float inv = 1.f / sum;

    for (int c = 0; c < nc; ++c) {
        int i = beg + c * 16 + slot;
        if (i < end) {
            float ex = (c < 4) ? av[c] : expf(rawv(i) - m);
            float a = ex * inv;
            alpha_csr[i * 4 + h] = a;
            aout[csr_eid[i] * 4 + h] = a;
        }
    }
}

// Wt[z][n][k] = bf16(W[z][k][n])  -- 64x64 LDS-tile transpose, coalesced both ways
#define WTP 72
__global__ __launch_bounds__(256) void k_wconv_t(const float* __restrict__ W,
                                                 unsigned short* __restrict__ Wt) {
    int bid = blockIdx.x;
    int z = bid >> 4;
    int tile = bid & 15;
    int k0 = (tile >> 2) * 64, n0 = (tile & 3) * 64;
    __shared__ unsigned short T[64 * WTP];
    int t = threadIdx.x;
    const float* Wz = W + ((size_t)z << 16);
    int r = t >> 4;
    int cs = (t & 15) * 4;
#pragma unroll
    for (int rr = 0; rr < 4; ++rr) {
        int k = r + rr * 16;
        float4 v = *(const float4*)(Wz + (size_t)(k0 + k) * 256 + n0 + cs);
        T[(cs + 0) * WTP + k] = f2bf(v.x);
        T[(cs + 1) * WTP + k] = f2bf(v.y);
        T[(cs + 2) * WTP + k] = f2bf(v.z);
        T[(cs + 3) * WTP + k] = f2bf(v.w);
    }
    __syncthreads();
    int n = t >> 2, ck = (t & 3) * 16;
    unsigned short* dst = Wt + ((size_t)z << 16) + (size_t)(n0 + n) * 256 + k0 + ck;
    const unsigned short* srcp = T + n * WTP + ck;
    *(uint4*)(dst) = *(const uint4*)(srcp);
    *(uint4*)(dst + 8) = *(const uint4*)(srcp + 8);
}

// ---------------- bf16 MFMA GEMM: 2-phase pipelined m97 structure ----------------
// 256 thr = 4 waves; tile 128x128, BK=32; double-buffered LDS.
// Per iteration: STAGE(next tile via global_load_lds 16B) FIRST, then ds_read+MFMA
// of current tile, then ONE __syncthreads (its vmcnt(0) drain waits only on loads
// issued a full compute-phase earlier -> latency hidden).
// Bank-conflict fix (rule #21, both-sides XOR): source col-group pre-swizzled with
// (lane&3)^((lane>>3)&3); ds_read applies kq^((lrow>>1)&3). 8-way -> 2-way (free).
// z < zlin (or zlin<0): Cbf[z][M][256] = bf16(A@B[z])
// z == zlin          : Cf = A@B[z] + bias + bias2   (fp32, full store)
#define TM 128
#define TN 128
__global__ __launch_bounds__(256) void gemm_mfma4(
    const unsigned short* __restrict__ A, const unsigned short* __restrict__ Bt,
    unsigned short* __restrict__ Cbf, float* __restrict__ Cf,
    const float* __restrict__ bias, const float* __restrict__ bias2,
    int M, int NZ, int NT, int MT, int zlin)
{
    __shared__ unsigned short As[2][128 * 32];
    __shared__ unsigned short Bs[2][128 * 32];

    int bi = blockIdx.x;
    int cx = bi & 7;
    int g = bi >> 3;
    int per = NZ * NT;
    int mh = g / per;
    int j  = g % per;
    int mt = mh * 8 + cx;
    if (mt >= MT) return;
    int z  = j % NZ;
    int nb = j / NZ;
    int m0 = mt * TM;
    int n0 = nb * TN;

    const unsigned short* Bz = Bt + ((size_t)z << 16);
    int t = threadIdx.x;
    int wave = t >> 6, lane = t & 63;
    int wr = wave >> 1, wc = wave & 1;
    int lrow = lane & 15, kq = lane >> 4;

    // staging: each wave DMAs 2x1024B chunks of As and Bs per K-step.
    // chunk q covers LDS rows [(wave*2+q)*16, +16); lane l -> row l>>2.
    // source col-group pre-swizzled so that LDS[row][gp] = global[row][gp ^ s(row)],
    // s(row) = (row>>1)&3 = (l>>3)&3 within a 16-row chunk.
    int sr0 = (wave * 2 + 0) * 16 + (lane >> 2);
    int sr1 = (wave * 2 + 1) * 16 + (lane >> 2);
    int sc = (((lane & 3) ^ ((lane >> 3) & 3))) * 8;
    int gm0 = m0 + sr0; if (gm0 >= M) gm0 = M - 1;  // clamp: dup rows never stored
    int gm1 = m0 + sr1; if (gm1 >= M) gm1 = M - 1;
    const unsigned short* gA0 = A + (size_t)gm0 * 256 + sc;
    const unsigned short* gA1 = A + (size_t)gm1 * 256 + sc;
    const unsigned short* gB0 = Bz + (size_t)(n0 + sr0) * 256 + sc;
    const unsigned short* gB1 = Bz + (size_t)(n0 + sr1) * 256 + sc;

    auto stage = [&](int b, int ko) {
        gl2l16(gA0 + ko, &As[b][(wave * 2 + 0) * 512]);
        gl2l16(gA1 + ko, &As[b][(wave * 2 + 1) * 512]);
        gl2l16(gB0 + ko, &Bs[b][(wave * 2 + 0) * 512]);
        gl2l16(gB1 + ko, &Bs[b][(wave * 2 + 1) * 512]);
    };

    // read-side swizzled K-group byte offset (in elements)
    int rg = (kq ^ ((lrow >> 1) & 3)) * 8;

    f32x4 acc[4][4];
#pragma unroll
    for (int i = 0; i < 4; ++i)
#pragma unroll
        for (int jj = 0; jj < 4; ++jj) acc[i][jj] = (f32x4){0.f, 0.f, 0.f, 0.f};

    // prologue: stage tile 0 into buffer 0
    stage(0, 0);
    __syncthreads();

    int cur = 0;
#pragma unroll 1
    for (int step = 0; step < 8; ++step) {
        if (step < 7) stage(cur ^ 1, (step + 1) * 32);   // prefetch next K-tile
        short8 af[4], bf4[4];
#pragma unroll
        for (int i = 0; i < 4; ++i)
            af[i] = *(const short8*)(&As[cur][(wr * 64 + i * 16 + lrow) * 32 + rg]);
#pragma unroll
        for (int jj = 0; jj < 4; ++jj)
            bf4[jj] = *(const short8*)(&Bs[cur][(wc * 64 + jj * 16 + lrow) * 32 + rg]);
#pragma unroll
        for (int i = 0; i < 4; ++i)
#pragma unroll
            for (int jj = 0; jj < 4; ++jj)
                acc[i][jj] = __builtin_amdgcn_mfma_f32_16x16x32_bf16(af[i], bf4[jj],
                                                                     acc[i][jj], 0, 0, 0);
        __syncthreads();   // single barrier: drains next-tile loads after compute
        cur ^= 1;
    }
    // C/D layout: row = kq*4 + reg, col = lrow
    if (z == zlin) {
#pragma unroll
        for (int i = 0; i < 4; ++i)
#pragma unroll
            for (int jj = 0; jj < 4; ++jj) {
                int gn = n0 + wc * 64 + jj * 16 + lrow;
                float bsum = bias[gn] + bias2[gn];
#pragma unroll
                for (int reg = 0; reg < 4; ++reg) {
                    int gm = m0 + wr * 64 + i * 16 + kq * 4 + reg;
                    if (gm < M) Cf[(size_t)gm * 256 + gn] = acc[i][jj][reg] + bsum;
                }
            }
    } else {
#pragma unroll
        for (int i = 0; i < 4; ++i)
#pragma unroll
            for (int jj = 0; jj < 4; ++jj) {
                int gn = n0 + wc * 64 + jj * 16 + lrow;
#pragma unroll
                for (int reg = 0; reg < 4; ++reg) {
                    int gm = m0 + wr * 64 + i * 16 + kq * 4 + reg;
                    if (gm < M)
                        Cbf[((size_t)z * M + gm) * 256 + gn] = f2bf(acc[i][jj][reg]);
                }
            }
    }
}

// ---------------- message aggregation: 2 waves per node, LDS combine ----------
// Block 256 thr = 4 waves = 2 nodes; wave parity p handles edges beg+p, beg+p+2, ...
__global__ __launch_bounds__(256) void k_msg_gather(
    const int* __restrict__ rowptr, const int* __restrict__ csr_se,
    const float* __restrict__ alpha_csr, const unsigned short* __restrict__ xw,
    const float* __restrict__ bias, float* __restrict__ out,
    unsigned short* __restrict__ xbout, int r0, int r1, int first, int act) {
    __shared__ float Pf[2][256];
    int tid = threadIdx.x;
    int wave = tid >> 6, lane = tid & 63;
    int nslot = wave >> 1, p = wave & 1;
    int node = blockIdx.x * 2 + nslot;
    int hsel = lane >> 4;
    float ax = 0.f, ay = 0.f, az = 0.f, aw = 0.f;

    auto edge = [&](int i) {
        int se = csr_se[i];
        int tt = se >> 16;
        if (tt >= r0 && tt < r1) {
            int s = se & 0xFFFF;
            float a = alpha_csr[i * 4 + hsel];
            uint2 pv = *(const uint2*)(xw + ((size_t)(tt - r0) * N + s) * 256 + lane * 4);
            ax += a * __uint_as_float(pv.x << 16);
            ay += a * __uint_as_float(pv.x & 0xFFFF0000u);
            az += a * __uint_as_float(pv.y << 16);
            aw += a * __uint_as_float(pv.y & 0xFFFF0000u);
        }
    };

    if (node < N) {
        int beg = rowptr[node], end = rowptr[node + 1];
        int i = beg + p;
        for (; i + 2 < end; i += 4) { edge(i); edge(i + 2); }
        if (i < end) edge(i);
    }
    if (p == 1) {
        float4 v = {ax, ay, az, aw};
        *(float4*)(&Pf[nslot][lane * 4]) = v;
    }
    __syncthreads();
    if (p == 0 && node < N) {
        float4 q = *(const float4*)(&Pf[nslot][lane * 4]);
        ax += q.x; ay += q.y; az += q.z; aw += q.w;
        float* o = out + (size_t)node * 256 + lane * 4;
        float vx, vy, vz, vw;
        if (first) {
            const float4 b = ((const float4*)bias)[lane];
            vx = ax + b.x; vy = ay + b.y; vz = az + b.z; vw = aw + b.w;
        } else {
            vx = o[0] + ax; vy = o[1] + ay; vz = o[2] + az; vw = o[3] + aw;
        }
        if (act) {
            vx = lrelu(vx, 0.01f); vy = lrelu(vy, 0.01f);
            vz = lrelu(vz, 0.01f); vw = lrelu(vw, 0.01f);
            unsigned short* xo = xbout + (size_t)node * 256 + lane * 4;
            xo[0] = f2bf(vx); xo[1] = f2bf(vy); xo[2] = f2bf(vz); xo[3] = f2bf(vw);
        }
        o[0] = vx; o[1] = vy; o[2] = vz; o[3] = vw;
    }
}

extern "C" void kernel_launch(void* const* d_in, const int* in_sizes, int n_in,
                              void* d_out, int out_size, void* d_ws, size_t ws_size,
                              hipStream_t stream) {
    const float* kg   = (const float*)d_in[0];
    const float* cc0  = (const float*)d_in[1];
    const float* gw1  = (const float*)d_in[2];
    const float* gb1  = (const float*)d_in[3];
    const float* gw2  = (const float*)d_in[4];
    const float* gb2  = (const float*)d_in[5];
    const float* r1w  = (const float*)d_in[6];
    const float* r1q  = (const float*)d_in[7];
    const float* r1k  = (const float*)d_in[8];
    const float* r1b  = (const float*)d_in[9];
    const float* r2w  = (const float*)d_in[10];
    const float* r2q  = (const float*)d_in[11];
    const float* r2k  = (const float*)d_in[12];
    const float* r2b  = (const float*)d_in[13];
    const float* linw = (const float*)d_in[14];
    const float* linb = (const float*)d_in[15];
    const int*   ei   = (const int*)d_in[16];
    const int*   et   = (const int*)d_in[17];

    float* out = (float*)d_out;
    float* a1  = out + (size_t)N * C;
    float* a2  = a1 + (size_t)E * H;

    float* ws = (float*)d_ws;
    size_t off = 0;
    float* dis  = ws + off; off += N;
    float* h1   = ws + off; off += (size_t)N * 32;
    float* c1   = ws + off; off += (size_t)N * 32;
    unsigned short* h2b = (unsigned short*)(ws + off); off += (size_t)N * 64;
    float* x0   = ws + off; off += (size_t)N * C;
    float* hmid = ws + off; off += (size_t)N * C;
    float* qn   = ws + off; off += (size_t)N * R * H;
    float* kn   = ws + off; off += (size_t)N * R * H;
    int* cnt     = (int*)(ws + off); off += N;
    int* rowptr  = (int*)(ws + off); off += N + 1;
    int* cursor  = (int*)(ws + off); off += N;
    int* csr_se  = (int*)(ws + off); off += E;
    int* csr_eid = (int*)(ws + off); off += E;
    float* alpha = ws + off; off += (size_t)E * H;
    unsigned short* xb0 = (unsigned short*)(ws + off); off += (size_t)N * 128;
    unsigned short* xb1 = (unsigned short*)(ws + off); off += (size_t)N * 128;
    // wt[0..R-1] = RGAT weights (transposed bf16); wt[R] = lin weight -> contiguous
    unsigned short* wt  = (unsigned short*)(ws + off); off += (size_t)(R + 1) * 32768;
    unsigned short* wtl = wt + ((size_t)R << 16);
    unsigned short* wqkb = (unsigned short*)(ws + off); off += 8192;
    unsigned short* xwb = (unsigned short*)(ws + off);

    size_t fixedB = off * 4;
    int K = R;
    if (ws_size > fixedB) {
        size_t kmax = (ws_size - fixedB) / ((size_t)N * C * 2);
        if (kmax < (size_t)K) K = (int)kmax;
    } else {
        K = 1;
    }
    if (K < 1) K = 1;

    const int B = 256;
    auto cdiv = [](long a, long b) { return (int)((a + b - 1) / b); };
    const int MT = cdiv(N, TM);  // 157 m-tiles
    const int NT = C / TN;       // 2

    // ---- CSR build ----
    k_zero_int<<<cdiv(N, B), B, 0, stream>>>(cnt, N);
    k_count<<<cdiv(E, B), B, 0, stream>>>(ei, cnt);
    k_scan<<<1, 1024, 0, stream>>>(cnt, rowptr, cursor, dis);
    k_scatter<<<cdiv(E, B), B, 0, stream>>>(ei, et, cursor, csr_se, csr_eid);

    // ---- GCN ----
    k_h1<<<cdiv((long)N * 32, B), B, 0, stream>>>(cc0, gw1, h1);
    k_agg32<<<cdiv((long)N * 32, B), B, 0, stream>>>(rowptr, csr_se, dis, h1, gb1, c1);
    k_h2kg<<<cdiv((long)N * 128, B), B, 0, stream>>>(c1, gw2, kg, h2b, x0, xb0);
    k_agg128<<<cdiv((long)N * 128, B), B, 0, stream>>>(rowptr, csr_se, dis, h2b,
                                                       gb2, x0, xb0);

    auto rgat = [&](unsigned short* xb, const float* W,
                    const float* q, const float* kk, const float* b,
                    float* obuf, unsigned short* xbout, float* aout,
                    int first, int act, int lin, float* linout,
                    const float* lb1, const float* lb2) {
        k_wqkb<<<512, 256, 0, stream>>>(W, q, kk, wqkb);
        k_qnkn_mfma<<<cdiv(N, 64), B, 0, stream>>>(xb, wqkb, qn, kn);
        k_soft<<<cdiv((long)N * 64, B), B, 0, stream>>>(rowptr, csr_se, csr_eid,
                                                        qn, kn, alpha, aout);
        k_wconv_t<<<R * 16, 256, 0, stream>>>(W, wt);
        for (int r0 = 0; r0 < R; r0 += K) {
            int kc = (R - r0) < K ? (R - r0) : K;
            int addlin = (lin && (r0 + kc == R)) ? 1 : 0;
            int nz = kc + addlin;
            int zl = addlin ? kc : -1;
            int gx = 8 * nz * NT * cdiv(MT, 8);
            gemm_mfma4<<<gx, 256, 0, stream>>>(xb, wt + ((size_t)r0 << 16), xwb,
                                               linout, lb1, lb2,
                                               N, nz, NT, MT, zl);
            int last = (r0 + kc >= R) ? 1 : 0;
            k_msg_gather<<<cdiv(N, 2), 256, 0, stream>>>(
                rowptr, csr_se, alpha, xwb, b, obuf, xbout, r0, r0 + kc,
                (first && r0 == 0) ? 1 : 0, act && last);
        }
    };

    // residual-linear weight transposed into wt[R] before layer 1
    k_wconv_t<<<16, 256, 0, stream>>>(linw, wtl);

    // layer 1: hmid = r1b + messages (leaky fused, emits xb1 bf16);
    //          merged z=8 slice writes out = x0@linw + (linb + r2b)
    rgat(xb0, r1w, r1q, r1k, r1b, hmid, xb1, a1, 1, 1,
         1, out, linb, r2b);

    // layer 2: out += messages (bias already folded into linear epilogue)
    rgat(xb1, r2w, r2q, r2k, r2b, out, nullptr, a2, 0, 0,
         0, nullptr, nullptr, nullptr);
}

// Round 3
// 525.292 us; speedup vs baseline: 1.0072x; 1.0072x over previous
//
#include <hip/hip_runtime.h>
#include <cstdint>

static constexpr int N = 20000;
static constexpr int E = 320000;
static constexpr int R = 8;
static constexpr int H = 4;
static constexpr int C = 256;

using short8 = __attribute__((ext_vector_type(8))) short;
using f32x4  = __attribute__((ext_vector_type(4))) float;
using us4    = __attribute__((ext_vector_type(4))) unsigned short;

__device__ __forceinline__ float lrelu(float x, float s) { return x >= 0.f ? x : s * x; }
__device__ __forceinline__ unsigned short f2bf(float f) {
    unsigned u = __float_as_uint(f);
    unsigned r = (u + 0x7FFFu + ((u >> 16) & 1u)) >> 16;
    return (unsigned short)r;
}
__device__ __forceinline__ float bf2f(unsigned short s) {
    return __uint_as_float(((unsigned)s) << 16);
}

// async global->LDS DMA, 16B per lane; LDS dest is wave-uniform base + lane*16
__device__ __forceinline__ void gl2l16(const unsigned short* g, unsigned short* l) {
    __builtin_amdgcn_global_load_lds(
        (const __attribute__((address_space(1))) unsigned int*)g,
        (__attribute__((address_space(3))) unsigned int*)l, 16, 0, 0);
}

// ---------------- CSR build ----------------
__global__ void k_zero_int(int* p, int n) {
    int i = blockIdx.x * blockDim.x + threadIdx.x;
    if (i < n) p[i] = 0;
}

__global__ void k_count(const int* __restrict__ ei, int* __restrict__ cnt) {
    int e = blockIdx.x * blockDim.x + threadIdx.x;
    if (e < E) atomicAdd(&cnt[ei[E + e]], 1);
}

// exclusive scan of cnt -> rowptr; also emits cursor copy and dis = rsqrt(cnt+1)
__global__ __launch_bounds__(1024) void k_scan(const int* __restrict__ cnt,
                                               int* __restrict__ rowptr,
                                               int* __restrict__ cursor,
                                               float* __restrict__ dis) {
    __shared__ int part[1024];
    const int CH = (N + 1023) / 1024;  // 20
    int t = threadIdx.x;
    int base = t * CH;
    int sum = 0;
    for (int j = 0; j < CH; ++j) {
        int idx = base + j;
        if (idx < N) sum += cnt[idx];
    }
    part[t] = sum;
    __syncthreads();
    for (int off = 1; off < 1024; off <<= 1) {
        int v = 0;
        if (t >= off) v = part[t - off];
        __syncthreads();
        if (t >= off) part[t] += v;
        __syncthreads();
    }
    int run = part[t] - sum;
    for (int j = 0; j < CH; ++j) {
        int idx = base + j;
        if (idx < N) {
            int cv = cnt[idx];
            rowptr[idx] = run;
            cursor[idx] = run;
            dis[idx] = rsqrtf((float)cv + 1.0f);
            run += cv;
        }
    }
    if (t == 1023) rowptr[N] = part[1023];
}

// csr_se packs (edge_type<<16)|src ; csr_eid keeps original edge id
__global__ void k_scatter(const int* __restrict__ ei, const int* __restrict__ et,
                          int* __restrict__ cursor, int* __restrict__ csr_se,
                          int* __restrict__ csr_eid) {
    int e = blockIdx.x * blockDim.x + threadIdx.x;
    if (e >= E) return;
    int d = ei[E + e];
    int pos = atomicAdd(&cursor[d], 1);
    csr_se[pos] = (et[e] << 16) | ei[e];
    csr_eid[pos] = e;
}

// ---------------- GCN ----------------
__global__ void k_h1(const float* __restrict__ x, const float* __restrict__ W,
                     float* __restrict__ h) {
    int idx = blockIdx.x * blockDim.x + threadIdx.x;
    if (idx >= N * 32) return;
    int n = idx >> 5, f = idx & 31;
    const float* xr = x + n * 4;
    float acc = 0.f;
#pragma unroll
    for (int c = 0; c < 4; ++c) acc += xr[c] * W[c * 32 + f];
    h[idx] = acc;
}

__global__ void k_agg32(const int* __restrict__ rowptr, const int* __restrict__ csr_se,
                        const float* __restrict__ dis, const float* __restrict__ h,
                        const float* __restrict__ b, float* __restrict__ c) {
    int idx = blockIdx.x * blockDim.x + threadIdx.x;
    if (idx >= N * 32) return;
    int d = idx >> 5, f = idx & 31;
    int beg = rowptr[d], end = rowptr[d + 1];
    float acc = 0.f;
    for (int i = beg; i < end; ++i) {
        int s = csr_se[i] & 0xFFFF;
        acc += dis[s] * h[s * 32 + f];
    }
    float dd = dis[d];
    c[idx] = dd * acc + dd * dd * h[idx] + b[f];
}

// h2 (bf16) + kg copy into x0/xb0, one dispatch
__global__ void k_h2kg(const float* __restrict__ c1, const float* __restrict__ W,
                       const float* __restrict__ kg, unsigned short* __restrict__ h,
                       float* __restrict__ x0, unsigned short* __restrict__ xb0) {
    int idx = blockIdx.x * blockDim.x + threadIdx.x;
    if (idx >= N * 128) return;
    int n = idx >> 7, f = idx & 127;
    const float* cr = c1 + n * 32;
    float acc = 0.f;
    for (int c = 0; c < 32; ++c) acc += lrelu(cr[c], 0.01f) * W[c * 128 + f];
    h[idx] = f2bf(acc);
    float v = kg[idx];
    x0[n * 256 + f] = v;
    xb0[n * 256 + f] = f2bf(v);
}

__global__ void k_agg128(const int* __restrict__ rowptr, const int* __restrict__ csr_se,
                         const float* __restrict__ dis,
                         const unsigned short* __restrict__ h,
                         const float* __restrict__ b, float* __restrict__ x0,
                         unsigned short* __restrict__ xb0) {
    int idx = blockIdx.x * blockDim.x + threadIdx.x;
    if (idx >= N * 128) return;
    int d = idx >> 7, f = idx & 127;
    int beg = rowptr[d], end = rowptr[d + 1];
    float acc = 0.f;
    int i = beg;
    for (; i + 2 <= end; i += 2) {
        int s0 = csr_se[i] & 0xFFFF;
        int s1 = csr_se[i + 1] & 0xFFFF;
        float d0 = dis[s0], d1 = dis[s1];
        float v0 = bf2f(h[s0 * 128 + f]), v1 = bf2f(h[s1 * 128 + f]);
        acc += d0 * v0 + d1 * v1;
    }
    if (i < end) {
        int s = csr_se[i] & 0xFFFF;
        acc += dis[s] * bf2f(h[s * 128 + f]);
    }
    float dd = dis[d];
    float v = dd * acc + dd * dd * bf2f(h[d * 128 + f]) + b[f];
    x0[d * 256 + 128 + f] = v;
    xb0[d * 256 + 128 + f] = f2bf(v);
}

// ---------------- RGAT attention ----------------
// wave-per-(r,i) W@q / W@k projection: coalesced row read + shuffle reduce.
// wqkb[n][k]: n<32 -> q proj (n = r*4+h), n>=32 -> k proj (n = 32+r*4+h)
__global__ __launch_bounds__(256) void k_wqkb(const float* __restrict__ W,
                                              const float* __restrict__ q,
                                              const float* __restrict__ kmat,
                                              unsigned short* __restrict__ wqkb) {
    int w = (blockIdx.x * blockDim.x + threadIdx.x) >> 6;  // 0..2047
    int lane = threadIdx.x & 63;
    int r = w >> 8, i = w & 255;
    const float* wr = W + ((size_t)(r * 256 + i)) * 256;
    float4 a = *(const float4*)(wr + lane * 4);
    float aq0 = 0.f, aq1 = 0.f, aq2 = 0.f, aq3 = 0.f;
    float ak0 = 0.f, ak1 = 0.f, ak2 = 0.f, ak3 = 0.f;
    int o = lane * 4;
    const float av[4] = {a.x, a.y, a.z, a.w};
#pragma unroll
    for (int j = 0; j < 4; ++j) {
        float4 qv = *(const float4*)(q + (o + j) * 4);
        float4 kv = *(const float4*)(kmat + (o + j) * 4);
        aq0 += av[j] * qv.x; aq1 += av[j] * qv.y;
        aq2 += av[j] * qv.z; aq3 += av[j] * qv.w;
        ak0 += av[j] * kv.x; ak1 += av[j] * kv.y;
        ak2 += av[j] * kv.z; ak3 += av[j] * kv.w;
    }
#pragma unroll
    for (int d = 1; d < 64; d <<= 1) {
        aq0 += __shfl_xor(aq0, d); aq1 += __shfl_xor(aq1, d);
        aq2 += __shfl_xor(aq2, d); aq3 += __shfl_xor(aq3, d);
        ak0 += __shfl_xor(ak0, d); ak1 += __shfl_xor(ak1, d);
        ak2 += __shfl_xor(ak2, d); ak3 += __shfl_xor(ak3, d);
    }
    if (lane == 0) {
        int nq = r * 4, nk = 32 + r * 4;
        wqkb[(nq + 0) * 256 + i] = f2bf(aq0);
        wqkb[(nq + 1) * 256 + i] = f2bf(aq1);
        wqkb[(nq + 2) * 256 + i] = f2bf(aq2);
        wqkb[(nq + 3) * 256 + i] = f2bf(aq3);
        wqkb[(nk + 0) * 256 + i] = f2bf(ak0);
        wqkb[(nk + 1) * 256 + i] = f2bf(ak1);
        wqkb[(nk + 2) * 256 + i] = f2bf(ak2);
        wqkb[(nk + 3) * 256 + i] = f2bf(ak3);
    }
}

// qn|kn = xb @ wqkb^T via MFMA.  Block: 256 thr = 4 waves, 64 rows per block.
// Operands SWAPPED (mfma(b,a,acc) computes C^T): D-row = output col (kq*4+reg),
// D-col = node row (lrow) -> each lane holds 4 consecutive cols of one node row
// -> float4 stores.
#define QP 264
__global__ __launch_bounds__(256) void k_qnkn_mfma(
    const unsigned short* __restrict__ xb, const unsigned short* __restrict__ wqkb,
    float* __restrict__ qn, float* __restrict__ kn)
{
    __shared__ unsigned short Ws[64 * QP];
    int t = threadIdx.x;
    {
        int r = t >> 2, off = (t & 3) * 64;
#pragma unroll
        for (int i = 0; i < 8; ++i)
            *(uint4*)(&Ws[r * QP + off + i * 8]) =
                *(const uint4*)(wqkb + r * 256 + off + i * 8);
    }
    __syncthreads();
    int wave = t >> 6, lane = t & 63;
    int lrow = lane & 15, kq = lane >> 4;
    int mw = blockIdx.x * 64 + wave * 16;
    int gm = mw + lrow;
    int gmc = gm < N ? gm : N - 1;

    f32x4 acc[4];
#pragma unroll
    for (int j = 0; j < 4; ++j) acc[j] = (f32x4){0.f, 0.f, 0.f, 0.f};

    for (int k0 = 0; k0 < 8; ++k0) {
        short8 af = *(const short8*)(xb + (size_t)gmc * 256 + k0 * 32 + kq * 8);
#pragma unroll
        for (int j = 0; j < 4; ++j) {
            short8 bf4 = *(const short8*)(&Ws[(j * 16 + lrow) * QP + k0 * 32 + kq * 8]);
            acc[j] = __builtin_amdgcn_mfma_f32_16x16x32_bf16(bf4, af, acc[j], 0, 0, 0);
        }
    }
    if (gm < N) {
#pragma unroll
        for (int j = 0; j < 4; ++j) {
            int colb = j * 16 + kq * 4;
            float4 v = {acc[j][0], acc[j][1], acc[j][2], acc[j][3]};
            if (colb < 32) *(float4*)(qn + (size_t)gm * 32 + colb) = v;
            else           *(float4*)(kn + (size_t)gm * 32 + (colb - 32)) = v;
        }
    }
}

// wave-per-node softmax: lanes = 16 edge-slots x 4 heads, shuffle reductions.
__global__ void k_soft(const int* __restrict__ rowptr, const int* __restrict__ csr_se,
                       const int* __restrict__ csr_eid,
                       const float* __restrict__ qn, const float* __restrict__ kn,
                       float* __restrict__ alpha_csr, float* __restrict__ aout) {
    int wid = (blockIdx.x * blockDim.x + threadIdx.x) >> 6;
    int lane = threadIdx.x & 63;
    if (wid >= N) return;
    int d = wid;
    int beg = rowptr[d], end = rowptr[d + 1];
    if (beg >= end) return;
    int slot = lane >> 2, h = lane & 3;
    int nc = (end - beg + 15) >> 4;
    const float* qrow = qn + d * 32;

    auto rawv = [&](int i) {
        int se = csr_se[i];
        int tt = se >> 16, s = se & 0xFFFF;
        return lrelu(qrow[tt * 4 + h] + kn[s * 32 + tt * 4 + h], 0.2f);
    };

    float av[4];
    float m = -1e30f;
    for (int c = 0; c < nc; ++c) {
        int i = beg + c * 16 + slot;
        float v = (i < end) ? rawv(i) : -1e30f;
        if (c < 4) av[c] = v;
        m = fmaxf(m, v);
    }
    m = fmaxf(m, __shfl_xor(m, 4));
    m = fmaxf(m, __shfl_xor(m, 8));
    m = fmaxf(m, __shfl_xor(m, 16));
    m = fmaxf(m, __shfl_xor(m, 32));

    float sum = 0.f;
    for (int c = 0; c < nc; ++c) {
        int i = beg + c * 16 + slot;
        float ex = 0.f;
        if (i < end) {
            float v = (c < 4) ? av[c] : rawv(i);
            ex = expf(v - m);
        }
        if (c < 4) av[c] = ex;
        sum += ex;
    }
    sum += __shfl_xor(sum, 4);
    sum += __shfl_xor(sum, 8);
    sum += __shfl_xor(sum, 16);
    sum += __shfl_xor(sum, 32);
    float inv = 1.f / sum;

    for (int c = 0; c < nc; ++c) {
        int i = beg + c * 16 + slot;
        if (i < end) {
            float ex = (c < 4) ? av[c] : expf(rawv(i) - m);
            float a = ex * inv;
            alpha_csr[i * 4 + h] = a;
            aout[csr_eid[i] * 4 + h] = a;
        }
    }
}

// Wt[z][n][k] = bf16(W[z][k][n])  -- 64x64 LDS-tile transpose, coalesced both ways
#define WTP 72
__global__ __launch_bounds__(256) void k_wconv_t(const float* __restrict__ W,
                                                 unsigned short* __restrict__ Wt) {
    int bid = blockIdx.x;
    int z = bid >> 4;
    int tile = bid & 15;
    int k0 = (tile >> 2) * 64, n0 = (tile & 3) * 64;
    __shared__ unsigned short T[64 * WTP];
    int t = threadIdx.x;
    const float* Wz = W + ((size_t)z << 16);
    int r = t >> 4;
    int cs = (t & 15) * 4;
#pragma unroll
    for (int rr = 0; rr < 4; ++rr) {
        int k = r + rr * 16;
        float4 v = *(const float4*)(Wz + (size_t)(k0 + k) * 256 + n0 + cs);
        T[(cs + 0) * WTP + k] = f2bf(v.x);
        T[(cs + 1) * WTP + k] = f2bf(v.y);
        T[(cs + 2) * WTP + k] = f2bf(v.z);
        T[(cs + 3) * WTP + k] = f2bf(v.w);
    }
    __syncthreads();
    int n = t >> 2, ck = (t & 3) * 16;
    unsigned short* dst = Wt + ((size_t)z << 16) + (size_t)(n0 + n) * 256 + k0 + ck;
    const unsigned short* srcp = T + n * WTP + ck;
    *(uint4*)(dst) = *(const uint4*)(srcp);
    *(uint4*)(dst + 8) = *(const uint4*)(srcp + 8);
}

// ---------------- bf16 MFMA GEMM: m97 structure + swizzle + C^T epilogue -------
// 256 thr = 4 waves; tile 128x128, BK=32; single-buffer LDS (16KB -> occupancy);
// global_load_lds(16B) staging, 2 barriers per K-step.
// Bank-conflict fix (rule #21 both-sides XOR): source col-group pre-swizzled with
// (lane&3)^((lane>>3)&3); ds_read applies kq^((lrow>>1)&3).  8-way -> 2-way (free).
// MFMA operands SWAPPED: D-row = n (kq*4+reg), D-col = m (lrow) -> each lane holds
// 4 consecutive output cols of one row -> ushort4/float4 vector stores.
// z < zlin (or zlin<0): Cbf[z][M][256] = bf16(A@B[z])
// z == zlin          : Cf = A@B[z] + bias + bias2   (fp32, full store)
#define TM 128
#define TN 128
__global__ __launch_bounds__(256) void gemm_mfma4(
    const unsigned short* __restrict__ A, const unsigned short* __restrict__ Bt,
    unsigned short* __restrict__ Cbf, float* __restrict__ Cf,
    const float* __restrict__ bias, const float* __restrict__ bias2,
    int M, int NZ, int NT, int MT, int zlin)
{
    __shared__ unsigned short As[128 * 32];
    __shared__ unsigned short Bs[128 * 32];

    int bi = blockIdx.x;
    int cx = bi & 7;
    int g = bi >> 3;
    int per = NZ * NT;
    int mh = g / per;
    int j  = g % per;
    int mt = mh * 8 + cx;
    if (mt >= MT) return;
    int z  = j % NZ;
    int nb = j / NZ;
    int m0 = mt * TM;
    int n0 = nb * TN;

    const unsigned short* Bz = Bt + ((size_t)z << 16);
    int t = threadIdx.x;
    int wave = t >> 6, lane = t & 63;
    int wr = wave >> 1, wc = wave & 1;
    int lrow = lane & 15, kq = lane >> 4;

    // staging: each wave DMAs 2x1024B chunks of As and Bs per K-step.
    // chunk q covers LDS rows [(wave*2+q)*16, +16); lane l -> row l>>2.
    // source col-group pre-swizzled: LDS[row][gp] = global[row][gp ^ ((row>>1)&3)]
    int sr0 = (wave * 2 + 0) * 16 + (lane >> 2);
    int sr1 = (wave * 2 + 1) * 16 + (lane >> 2);
    int sc = (((lane & 3) ^ ((lane >> 3) & 3))) * 8;
    int gm0 = m0 + sr0; if (gm0 >= M) gm0 = M - 1;  // clamp: dup rows never stored
    int gm1 = m0 + sr1; if (gm1 >= M) gm1 = M - 1;
    const unsigned short* gA0 = A + (size_t)gm0 * 256 + sc;
    const unsigned short* gA1 = A + (size_t)gm1 * 256 + sc;
    const unsigned short* gB0 = Bz + (size_t)(n0 + sr0) * 256 + sc;
    const unsigned short* gB1 = Bz + (size_t)(n0 + sr1) * 256 + sc;
    unsigned short* lA0 = &As[(wave * 2 + 0) * 512];
    unsigned short* lA1 = &As[(wave * 2 + 1) * 512];
    unsigned short* lB0 = &Bs[(wave * 2 + 0) * 512];
    unsigned short* lB1 = &Bs[(wave * 2 + 1) * 512];

    // read-side swizzled K-group offset (elements)
    int rg = (kq ^ ((lrow >> 1) & 3)) * 8;

    f32x4 acc[4][4];
#pragma unroll
    for (int i = 0; i < 4; ++i)
#pragma unroll
        for (int jj = 0; jj < 4; ++jj) acc[i][jj] = (f32x4){0.f, 0.f, 0.f, 0.f};

    for (int k0 = 0; k0 < 256; k0 += 32) {
        gl2l16(gA0 + k0, lA0);
        gl2l16(gA1 + k0, lA1);
        gl2l16(gB0 + k0, lB0);
        gl2l16(gB1 + k0, lB1);
        __syncthreads();   // drains vmcnt(0) before barrier
        short8 af[4], bf4[4];
#pragma unroll
        for (int i = 0; i < 4; ++i)
            af[i] = *(const short8*)(&As[(wr * 64 + i * 16 + lrow) * 32 + rg]);
#pragma unroll
        for (int jj = 0; jj < 4; ++jj)
            bf4[jj] = *(const short8*)(&Bs[(wc * 64 + jj * 16 + lrow) * 32 + rg]);
#pragma unroll
        for (int i = 0; i < 4; ++i)
#pragma unroll
            for (int jj = 0; jj < 4; ++jj)
                acc[i][jj] = __builtin_amdgcn_mfma_f32_16x16x32_bf16(bf4[jj], af[i],
                                                                     acc[i][jj], 0, 0, 0);
        __syncthreads();
    }
    // transposed D: each lane -> row gm = m0+wr*64+i*16+lrow,
    //               cols gnb..gnb+3 = n0+wc*64+jj*16+kq*4 ..
    if (z == zlin) {
#pragma unroll
        for (int i = 0; i < 4; ++i) {
            int gm = m0 + wr * 64 + i * 16 + lrow;
            if (gm >= M) continue;
#pragma unroll
            for (int jj = 0; jj < 4; ++jj) {
                int gnb = n0 + wc * 64 + jj * 16 + kq * 4;
                float4 b1 = *(const float4*)(bias + gnb);
                float4 b2 = *(const float4*)(bias2 + gnb);
                float4 v = {acc[i][jj][0] + b1.x + b2.x,
                            acc[i][jj][1] + b1.y + b2.y,
                            acc[i][jj][2] + b1.z + b2.z,
                            acc[i][jj][3] + b1.w + b2.w};
                *(float4*)(Cf + (size_t)gm * 256 + gnb) = v;
            }
        }
    } else {
#pragma unroll
        for (int i = 0; i < 4; ++i) {
            int gm = m0 + wr * 64 + i * 16 + lrow;
            if (gm >= M) continue;
#pragma unroll
            for (int jj = 0; jj < 4; ++jj) {
                int gnb = n0 + wc * 64 + jj * 16 + kq * 4;
                us4 v = {f2bf(acc[i][jj][0]), f2bf(acc[i][jj][1]),
                         f2bf(acc[i][jj][2]), f2bf(acc[i][jj][3])};
                *(us4*)(Cbf + ((size_t)z * M + gm) * 256 + gnb) = v;
            }
        }
    }
}

// ---------------- message aggregation: 2 waves per node, LDS combine ----------
// Block 256 thr = 4 waves = 2 nodes; wave parity p handles edges beg+p, beg+p+2, ...
__global__ __launch_bounds__(256) void k_msg_gather(
    const int* __restrict__ rowptr, const int* __restrict__ csr_se,
    const float* __restrict__ alpha_csr, const unsigned short* __restrict__ xw,
    const float* __restrict__ bias, float* __restrict__ out,
    unsigned short* __restrict__ xbout, int r0, int r1, int first, int act) {
    __shared__ float Pf[2][256];
    int tid = threadIdx.x;
    int wave = tid >> 6, lane = tid & 63;
    int nslot = wave >> 1, p = wave & 1;
    int node = blockIdx.x * 2 + nslot;
    int hsel = lane >> 4;
    float ax = 0.f, ay = 0.f, az = 0.f, aw = 0.f;

    auto edge = [&](int i) {
        int se = csr_se[i];
        int tt = se >> 16;
        if (tt >= r0 && tt < r1) {
            int s = se & 0xFFFF;
            float a = alpha_csr[i * 4 + hsel];
            uint2 pv = *(const uint2*)(xw + ((size_t)(tt - r0) * N + s) * 256 + lane * 4);
            ax += a * __uint_as_float(pv.x << 16);
            ay += a * __uint_as_float(pv.x & 0xFFFF0000u);
            az += a * __uint_as_float(pv.y << 16);
            aw += a * __uint_as_float(pv.y & 0xFFFF0000u);
        }
    };

    if (node < N) {
        int beg = rowptr[node], end = rowptr[node + 1];
        int i = beg + p;
        for (; i + 2 < end; i += 4) { edge(i); edge(i + 2); }
        if (i < end) edge(i);
    }
    if (p == 1) {
        float4 v = {ax, ay, az, aw};
        *(float4*)(&Pf[nslot][lane * 4]) = v;
    }
    __syncthreads();
    if (p == 0 && node < N) {
        float4 q = *(const float4*)(&Pf[nslot][lane * 4]);
        ax += q.x; ay += q.y; az += q.z; aw += q.w;
        float* o = out + (size_t)node * 256 + lane * 4;
        float vx, vy, vz, vw;
        if (first) {
            const float4 b = ((const float4*)bias)[lane];
            vx = ax + b.x; vy = ay + b.y; vz = az + b.z; vw = aw + b.w;
        } else {
            vx = o[0] + ax; vy = o[1] + ay; vz = o[2] + az; vw = o[3] + aw;
        }
        if (act) {
            vx = lrelu(vx, 0.01f); vy = lrelu(vy, 0.01f);
            vz = lrelu(vz, 0.01f); vw = lrelu(vw, 0.01f);
            unsigned short* xo = xbout + (size_t)node * 256 + lane * 4;
            xo[0] = f2bf(vx); xo[1] = f2bf(vy); xo[2] = f2bf(vz); xo[3] = f2bf(vw);
        }
        o[0] = vx; o[1] = vy; o[2] = vz; o[3] = vw;
    }
}

extern "C" void kernel_launch(void* const* d_in, const int* in_sizes, int n_in,
                              void* d_out, int out_size, void* d_ws, size_t ws_size,
                              hipStream_t stream) {
    const float* kg   = (const float*)d_in[0];
    const float* cc0  = (const float*)d_in[1];
    const float* gw1  = (const float*)d_in[2];
    const float* gb1  = (const float*)d_in[3];
    const float* gw2  = (const float*)d_in[4];
    const float* gb2  = (const float*)d_in[5];
    const float* r1w  = (const float*)d_in[6];
    const float* r1q  = (const float*)d_in[7];
    const float* r1k  = (const float*)d_in[8];
    const float* r1b  = (const float*)d_in[9];
    const float* r2w  = (const float*)d_in[10];
    const float* r2q  = (const float*)d_in[11];
    const float* r2k  = (const float*)d_in[12];
    const float* r2b  = (const float*)d_in[13];
    const float* linw = (const float*)d_in[14];
    const float* linb = (const float*)d_in[15];
    const int*   ei   = (const int*)d_in[16];
    const int*   et   = (const int*)d_in[17];

    float* out = (float*)d_out;
    float* a1  = out + (size_t)N * C;
    float* a2  = a1 + (size_t)E * H;

    float* ws = (float*)d_ws;
    size_t off = 0;
    float* dis  = ws + off; off += N;
    float* h1   = ws + off; off += (size_t)N * 32;
    float* c1   = ws + off; off += (size_t)N * 32;
    unsigned short* h2b = (unsigned short*)(ws + off); off += (size_t)N * 64;
    float* x0   = ws + off; off += (size_t)N * C;
    float* hmid = ws + off; off += (size_t)N * C;
    float* qn   = ws + off; off += (size_t)N * R * H;
    float* kn   = ws + off; off += (size_t)N * R * H;
    int* cnt     = (int*)(ws + off); off += N;
    int* rowptr  = (int*)(ws + off); off += N + 1;
    int* cursor  = (int*)(ws + off); off += N;
    int* csr_se  = (int*)(ws + off); off += E;
    int* csr_eid = (int*)(ws + off); off += E;
    float* alpha = ws + off; off += (size_t)E * H;
    unsigned short* xb0 = (unsigned short*)(ws + off); off += (size_t)N * 128;
    unsigned short* xb1 = (unsigned short*)(ws + off); off += (size_t)N * 128;
    // wt[0..R-1] = RGAT weights (transposed bf16); wt[R] = lin weight -> contiguous
    unsigned short* wt  = (unsigned short*)(ws + off); off += (size_t)(R + 1) * 32768;
    unsigned short* wtl = wt + ((size_t)R << 16);
    unsigned short* wqkb = (unsigned short*)(ws + off); off += 8192;
    unsigned short* xwb = (unsigned short*)(ws + off);

    size_t fixedB = off * 4;
    int K = R;
    if (ws_size > fixedB) {
        size_t kmax = (ws_size - fixedB) / ((size_t)N * C * 2);
        if (kmax < (size_t)K) K = (int)kmax;
    } else {
        K = 1;
    }
    if (K < 1) K = 1;

    const int B = 256;
    auto cdiv = [](long a, long b) { return (int)((a + b - 1) / b); };
    const int MT = cdiv(N, TM);  // 157 m-tiles
    const int NT = C / TN;       // 2

    // ---- CSR build ----
    k_zero_int<<<cdiv(N, B), B, 0, stream>>>(cnt, N);
    k_count<<<cdiv(E, B), B, 0, stream>>>(ei, cnt);
    k_scan<<<1, 1024, 0, stream>>>(cnt, rowptr, cursor, dis);
    k_scatter<<<cdiv(E, B), B, 0, stream>>>(ei, et, cursor, csr_se, csr_eid);

    // ---- GCN ----
    k_h1<<<cdiv((long)N * 32, B), B, 0, stream>>>(cc0, gw1, h1);
    k_agg32<<<cdiv((long)N * 32, B), B, 0, stream>>>(rowptr, csr_se, dis, h1, gb1, c1);
    k_h2kg<<<cdiv((long)N * 128, B), B, 0, stream>>>(c1, gw2, kg, h2b, x0, xb0);
    k_agg128<<<cdiv((long)N * 128, B), B, 0, stream>>>(rowptr, csr_se, dis, h2b,
                                                       gb2, x0, xb0);

    auto rgat = [&](unsigned short* xb, const float* W,
                    const float* q, const float* kk, const float* b,
                    float* obuf, unsigned short* xbout, float* aout,
                    int first, int act, int lin, float* linout,
                    const float* lb1, const float* lb2) {
        k_wqkb<<<512, 256, 0, stream>>>(W, q, kk, wqkb);
        k_qnkn_mfma<<<cdiv(N, 64), B, 0, stream>>>(xb, wqkb, qn, kn);
        k_soft<<<cdiv((long)N * 64, B), B, 0, stream>>>(rowptr, csr_se, csr_eid,
                                                        qn, kn, alpha, aout);
        k_wconv_t<<<R * 16, 256, 0, stream>>>(W, wt);
        for (int r0 = 0; r0 < R; r0 += K) {
            int kc = (R - r0) < K ? (R - r0) : K;
            int addlin = (lin && (r0 + kc == R)) ? 1 : 0;
            int nz = kc + addlin;
            int zl = addlin ? kc : -1;
            int gx = 8 * nz * NT * cdiv(MT, 8);
            gemm_mfma4<<<gx, 256, 0, stream>>>(xb, wt + ((size_t)r0 << 16), xwb,
                                               linout, lb1, lb2,
                                               N, nz, NT, MT, zl);
            int last = (r0 + kc >= R) ? 1 : 0;
            k_msg_gather<<<cdiv(N, 2), 256, 0, stream>>>(
                rowptr, csr_se, alpha, xwb, b, obuf, xbout, r0, r0 + kc,
                (first && r0 == 0) ? 1 : 0, act && last);
        }
    };

    // residual-linear weight transposed into wt[R] before layer 1
    k_wconv_t<<<16, 256, 0, stream>>>(linw, wtl);

    // layer 1: hmid = r1b + messages (leaky fused, emits xb1 bf16);
    //          merged z=8 slice writes out = x0@linw + (linb + r2b)
    rgat(xb0, r1w, r1q, r1k, r1b, hmid, xb1, a1, 1, 1,
         1, out, linb, r2b);

    // layer 2: out += messages (bias already folded into linear epilogue)
    rgat(xb1, r2w, r2q, r2k, r2b, out, nullptr, a2, 0, 0,
         0, nullptr, nullptr, nullptr);
}

// Round 4
// 524.613 us; speedup vs baseline: 1.0085x; 1.0013x over previous
//
#include <hip/hip_runtime.h>
#include <cstdint>

static constexpr int N = 20000;
static constexpr int E = 320000;
static constexpr int R = 8;
static constexpr int H = 4;
static constexpr int C = 256;

using short8 = __attribute__((ext_vector_type(8))) short;
using f32x4  = __attribute__((ext_vector_type(4))) float;
using us4    = __attribute__((ext_vector_type(4))) unsigned short;

__device__ __forceinline__ float lrelu(float x, float s) { return x >= 0.f ? x : s * x; }
__device__ __forceinline__ unsigned short f2bf(float f) {
    unsigned u = __float_as_uint(f);
    unsigned r = (u + 0x7FFFu + ((u >> 16) & 1u)) >> 16;
    return (unsigned short)r;
}
__device__ __forceinline__ float bf2f(unsigned short s) {
    return __uint_as_float(((unsigned)s) << 16);
}

// async global->LDS DMA, 16B per lane; LDS dest is wave-uniform base + lane*16
__device__ __forceinline__ void gl2l16(const unsigned short* g, unsigned short* l) {
    __builtin_amdgcn_global_load_lds(
        (const __attribute__((address_space(1))) unsigned int*)g,
        (__attribute__((address_space(3))) unsigned int*)l, 16, 0, 0);
}

// ---------------- CSR build ----------------
__global__ void k_zero_int(int* p, int n) {
    int i = blockIdx.x * blockDim.x + threadIdx.x;
    if (i < n) p[i] = 0;
}

__global__ void k_count(const int* __restrict__ ei, int* __restrict__ cnt) {
    int e = blockIdx.x * blockDim.x + threadIdx.x;
    if (e < E) atomicAdd(&cnt[ei[E + e]], 1);
}

// exclusive scan of cnt -> rowptr; also emits cursor copy and dis = rsqrt(cnt+1)
__global__ __launch_bounds__(1024) void k_scan(const int* __restrict__ cnt,
                                               int* __restrict__ rowptr,
                                               int* __restrict__ cursor,
                                               float* __restrict__ dis) {
    __shared__ int part[1024];
    const int CH = (N + 1023) / 1024;  // 20
    int t = threadIdx.x;
    int base = t * CH;
    int sum = 0;
    for (int j = 0; j < CH; ++j) {
        int idx = base + j;
        if (idx < N) sum += cnt[idx];
    }
    part[t] = sum;
    __syncthreads();
    for (int off = 1; off < 1024; off <<= 1) {
        int v = 0;
        if (t >= off) v = part[t - off];
        __syncthreads();
        if (t >= off) part[t] += v;
        __syncthreads();
    }
    int run = part[t] - sum;
    for (int j = 0; j < CH; ++j) {
        int idx = base + j;
        if (idx < N) {
            int cv = cnt[idx];
            rowptr[idx] = run;
            cursor[idx] = run;
            dis[idx] = rsqrtf((float)cv + 1.0f);
            run += cv;
        }
    }
    if (t == 1023) rowptr[N] = part[1023];
}

// csr_se packs (edge_type<<16)|src ; csr_eid keeps original edge id
__global__ void k_scatter(const int* __restrict__ ei, const int* __restrict__ et,
                          int* __restrict__ cursor, int* __restrict__ csr_se,
                          int* __restrict__ csr_eid) {
    int e = blockIdx.x * blockDim.x + threadIdx.x;
    if (e >= E) return;
    int d = ei[E + e];
    int pos = atomicAdd(&cursor[d], 1);
    csr_se[pos] = (et[e] << 16) | ei[e];
    csr_eid[pos] = e;
}

// ---------------- GCN ----------------
__global__ void k_h1(const float* __restrict__ x, const float* __restrict__ W,
                     float* __restrict__ h) {
    int idx = blockIdx.x * blockDim.x + threadIdx.x;
    if (idx >= N * 32) return;
    int n = idx >> 5, f = idx & 31;
    const float* xr = x + n * 4;
    float acc = 0.f;
#pragma unroll
    for (int c = 0; c < 4; ++c) acc += xr[c] * W[c * 32 + f];
    h[idx] = acc;
}

__global__ void k_agg32(const int* __restrict__ rowptr, const int* __restrict__ csr_se,
                        const float* __restrict__ dis, const float* __restrict__ h,
                        const float* __restrict__ b, float* __restrict__ c) {
    int idx = blockIdx.x * blockDim.x + threadIdx.x;
    if (idx >= N * 32) return;
    int d = idx >> 5, f = idx & 31;
    int beg = rowptr[d], end = rowptr[d + 1];
    float acc = 0.f;
    for (int i = beg; i < end; ++i) {
        int s = csr_se[i] & 0xFFFF;
        acc += dis[s] * h[s * 32 + f];
    }
    float dd = dis[d];
    c[idx] = dd * acc + dd * dd * h[idx] + b[f];
}

// h2 (bf16) + kg copy into x0/xb0, one dispatch
__global__ void k_h2kg(const float* __restrict__ c1, const float* __restrict__ W,
                       const float* __restrict__ kg, unsigned short* __restrict__ h,
                       float* __restrict__ x0, unsigned short* __restrict__ xb0) {
    int idx = blockIdx.x * blockDim.x + threadIdx.x;
    if (idx >= N * 128) return;
    int n = idx >> 7, f = idx & 127;
    const float* cr = c1 + n * 32;
    float acc = 0.f;
    for (int c = 0; c < 32; ++c) acc += lrelu(cr[c], 0.01f) * W[c * 128 + f];
    h[idx] = f2bf(acc);
    float v = kg[idx];
    x0[n * 256 + f] = v;
    xb0[n * 256 + f] = f2bf(v);
}

__global__ void k_agg128(const int* __restrict__ rowptr, const int* __restrict__ csr_se,
                         const float* __restrict__ dis,
                         const unsigned short* __restrict__ h,
                         const float* __restrict__ b, float* __restrict__ x0,
                         unsigned short* __restrict__ xb0) {
    int idx = blockIdx.x * blockDim.x + threadIdx.x;
    if (idx >= N * 128) return;
    int d = idx >> 7, f = idx & 127;
    int beg = rowptr[d], end = rowptr[d + 1];
    float acc = 0.f;
    int i = beg;
    for (; i + 2 <= end; i += 2) {
        int s0 = csr_se[i] & 0xFFFF;
        int s1 = csr_se[i + 1] & 0xFFFF;
        float d0 = dis[s0], d1 = dis[s1];
        float v0 = bf2f(h[s0 * 128 + f]), v1 = bf2f(h[s1 * 128 + f]);
        acc += d0 * v0 + d1 * v1;
    }
    if (i < end) {
        int s = csr_se[i] & 0xFFFF;
        acc += dis[s] * bf2f(h[s * 128 + f]);
    }
    float dd = dis[d];
    float v = dd * acc + dd * dd * bf2f(h[d * 128 + f]) + b[f];
    x0[d * 256 + 128 + f] = v;
    xb0[d * 256 + 128 + f] = f2bf(v);
}

// ---------------- RGAT attention ----------------
// wave-per-(r,i) W@q / W@k projection: coalesced row read + shuffle reduce.
// wqkb[n][k]: n<32 -> q proj (n = r*4+h), n>=32 -> k proj (n = 32+r*4+h)
__global__ __launch_bounds__(256) void k_wqkb(const float* __restrict__ W,
                                              const float* __restrict__ q,
                                              const float* __restrict__ kmat,
                                              unsigned short* __restrict__ wqkb) {
    int w = (blockIdx.x * blockDim.x + threadIdx.x) >> 6;  // 0..2047
    int lane = threadIdx.x & 63;
    int r = w >> 8, i = w & 255;
    const float* wr = W + ((size_t)(r * 256 + i)) * 256;
    float4 a = *(const float4*)(wr + lane * 4);
    float aq0 = 0.f, aq1 = 0.f, aq2 = 0.f, aq3 = 0.f;
    float ak0 = 0.f, ak1 = 0.f, ak2 = 0.f, ak3 = 0.f;
    int o = lane * 4;
    const float av[4] = {a.x, a.y, a.z, a.w};
#pragma unroll
    for (int j = 0; j < 4; ++j) {
        float4 qv = *(const float4*)(q + (o + j) * 4);
        float4 kv = *(const float4*)(kmat + (o + j) * 4);
        aq0 += av[j] * qv.x; aq1 += av[j] * qv.y;
        aq2 += av[j] * qv.z; aq3 += av[j] * qv.w;
        ak0 += av[j] * kv.x; ak1 += av[j] * kv.y;
        ak2 += av[j] * kv.z; ak3 += av[j] * kv.w;
    }
#pragma unroll
    for (int d = 1; d < 64; d <<= 1) {
        aq0 += __shfl_xor(aq0, d); aq1 += __shfl_xor(aq1, d);
        aq2 += __shfl_xor(aq2, d); aq3 += __shfl_xor(aq3, d);
        ak0 += __shfl_xor(ak0, d); ak1 += __shfl_xor(ak1, d);
        ak2 += __shfl_xor(ak2, d); ak3 += __shfl_xor(ak3, d);
    }
    if (lane == 0) {
        int nq = r * 4, nk = 32 + r * 4;
        wqkb[(nq + 0) * 256 + i] = f2bf(aq0);
        wqkb[(nq + 1) * 256 + i] = f2bf(aq1);
        wqkb[(nq + 2) * 256 + i] = f2bf(aq2);
        wqkb[(nq + 3) * 256 + i] = f2bf(aq3);
        wqkb[(nk + 0) * 256 + i] = f2bf(ak0);
        wqkb[(nk + 1) * 256 + i] = f2bf(ak1);
        wqkb[(nk + 2) * 256 + i] = f2bf(ak2);
        wqkb[(nk + 3) * 256 + i] = f2bf(ak3);
    }
}

// qn|kn = xb @ wqkb^T via MFMA.  Block: 256 thr = 4 waves, 64 rows per block.
// Operands SWAPPED (mfma(b,a,acc) computes C^T): D-row = output col (kq*4+reg),
// D-col = node row (lrow) -> each lane holds 4 consecutive cols of one node row
// -> float4 stores.
#define QP 264
__global__ __launch_bounds__(256) void k_qnkn_mfma(
    const unsigned short* __restrict__ xb, const unsigned short* __restrict__ wqkb,
    float* __restrict__ qn, float* __restrict__ kn)
{
    __shared__ unsigned short Ws[64 * QP];
    int t = threadIdx.x;
    {
        int r = t >> 2, off = (t & 3) * 64;
#pragma unroll
        for (int i = 0; i < 8; ++i)
            *(uint4*)(&Ws[r * QP + off + i * 8]) =
                *(const uint4*)(wqkb + r * 256 + off + i * 8);
    }
    __syncthreads();
    int wave = t >> 6, lane = t & 63;
    int lrow = lane & 15, kq = lane >> 4;
    int mw = blockIdx.x * 64 + wave * 16;
    int gm = mw + lrow;
    int gmc = gm < N ? gm : N - 1;

    f32x4 acc[4];
#pragma unroll
    for (int j = 0; j < 4; ++j) acc[j] = (f32x4){0.f, 0.f, 0.f, 0.f};

    for (int k0 = 0; k0 < 8; ++k0) {
        short8 af = *(const short8*)(xb + (size_t)gmc * 256 + k0 * 32 + kq * 8);
#pragma unroll
        for (int j = 0; j < 4; ++j) {
            short8 bf4 = *(const short8*)(&Ws[(j * 16 + lrow) * QP + k0 * 32 + kq * 8]);
            acc[j] = __builtin_amdgcn_mfma_f32_16x16x32_bf16(bf4, af, acc[j], 0, 0, 0);
        }
    }
    if (gm < N) {
#pragma unroll
        for (int j = 0; j < 4; ++j) {
            int colb = j * 16 + kq * 4;
            float4 v = {acc[j][0], acc[j][1], acc[j][2], acc[j][3]};
            if (colb < 32) *(float4*)(qn + (size_t)gm * 32 + colb) = v;
            else           *(float4*)(kn + (size_t)gm * 32 + (colb - 32)) = v;
        }
    }
}

// wave-per-node softmax: lanes = 16 edge-slots x 4 heads, shuffle reductions.
__global__ void k_soft(const int* __restrict__ rowptr, const int* __restrict__ csr_se,
                       const int* __restrict__ csr_eid,
                       const float* __restrict__ qn, const float* __restrict__ kn,
                       float* __restrict__ alpha_csr, float* __restrict__ aout) {
    int wid = (blockIdx.x * blockDim.x + threadIdx.x) >> 6;
    int lane = threadIdx.x & 63;
    if (wid >= N) return;
    int d = wid;
    int beg = rowptr[d], end = rowptr[d + 1];
    if (beg >= end) return;
    int slot = lane >> 2, h = lane & 3;
    int nc = (end - beg + 15) >> 4;
    const float* qrow = qn + d * 32;

    auto rawv = [&](int i) {
        int se = csr_se[i];
        int tt = se >> 16, s = se & 0xFFFF;
        return lrelu(qrow[tt * 4 + h] + kn[s * 32 + tt * 4 + h], 0.2f);
    };

    float av[4];
    float m = -1e30f;
    for (int c = 0; c < nc; ++c) {
        int i = beg + c * 16 + slot;
        float v = (i < end) ? rawv(i) : -1e30f;
        if (c < 4) av[c] = v;
        m = fmaxf(m, v);
    }
    m = fmaxf(m, __shfl_xor(m, 4));
    m = fmaxf(m, __shfl_xor(m, 8));
    m = fmaxf(m, __shfl_xor(m, 16));
    m = fmaxf(m, __shfl_xor(m, 32));

    float sum = 0.f;
    for (int c = 0; c < nc; ++c) {
        int i = beg + c * 16 + slot;
        float ex = 0.f;
        if (i < end) {
            float v = (c < 4) ? av[c] : rawv(i);
            ex = expf(v - m);
        }
        if (c < 4) av[c] = ex;
        sum += ex;
    }
    sum += __shfl_xor(sum, 4);
    sum += __shfl_xor(sum, 8);
    sum += __shfl_xor(sum, 16);
    sum += __shfl_xor(sum, 32);
    float inv = 1.f / sum;

    for (int c = 0; c < nc; ++c) {
        int i = beg + c * 16 + slot;
        if (i < end) {
            float ex = (c < 4) ? av[c] : expf(rawv(i) - m);
            float a = ex * inv;
            alpha_csr[i * 4 + h] = a;
            aout[csr_eid[i] * 4 + h] = a;
        }
    }
}

// Wt[z][n][k] = bf16(W[z][k][n])  -- 64x64 LDS-tile transpose, coalesced both ways
#define WTP 72
__global__ __launch_bounds__(256) void k_wconv_t(const float* __restrict__ W,
                                                 unsigned short* __restrict__ Wt) {
    int bid = blockIdx.x;
    int z = bid >> 4;
    int tile = bid & 15;
    int k0 = (tile >> 2) * 64, n0 = (tile & 3) * 64;
    __shared__ unsigned short T[64 * WTP];
    int t = threadIdx.x;
    const float* Wz = W + ((size_t)z << 16);
    int r = t >> 4;
    int cs = (t & 15) * 4;
#pragma unroll
    for (int rr = 0; rr < 4; ++rr) {
        int k = r + rr * 16;
        float4 v = *(const float4*)(Wz + (size_t)(k0 + k) * 256 + n0 + cs);
        T[(cs + 0) * WTP + k] = f2bf(v.x);
        T[(cs + 1) * WTP + k] = f2bf(v.y);
        T[(cs + 2) * WTP + k] = f2bf(v.z);
        T[(cs + 3) * WTP + k] = f2bf(v.w);
    }
    __syncthreads();
    int n = t >> 2, ck = (t & 3) * 16;
    unsigned short* dst = Wt + ((size_t)z << 16) + (size_t)(n0 + n) * 256 + k0 + ck;
    const unsigned short* srcp = T + n * WTP + ck;
    *(uint4*)(dst) = *(const uint4*)(srcp);
    *(uint4*)(dst + 8) = *(const uint4*)(srcp + 8);
}

// ---------------- bf16 MFMA GEMM: counted-vmcnt 2-deep pipeline (T3+T4) --------
// 256 thr = 4 waves; tile 128x128, BK=32; DOUBLE-buffered LDS (32KB);
// global_load_lds(16B) staging, 2-deep: tile t's loads issued 2 phases early.
// Loop NEVER drains vmcnt to 0 (except last iter): per-wave s_waitcnt vmcnt(4)
// + raw s_barrier publishes LDS (each wave waits its OWN loads, then barrier).
// sched_barrier(0) fences per rule #18; lgkmcnt(0) before barrier2 guarantees
// ds_reads consumed before buffer overwrite.
// Bank-conflict fix (rule #21 both-sides XOR): src col-group pre-swizzled with
// (lane&3)^((lane>>3)&3); ds_read applies kq^((lrow>>1)&3).
// MFMA operands SWAPPED: D-row = n, D-col = m -> vectorized ushort4/float4 stores.
// z < zlin (or zlin<0): Cbf[z][M][256] = bf16(A@B[z])
// z == zlin          : Cf = A@B[z] + bias + bias2   (fp32, full store)
#define TM 128
#define TN 128
__global__ __launch_bounds__(256) void gemm_mfma4(
    const unsigned short* __restrict__ A, const unsigned short* __restrict__ Bt,
    unsigned short* __restrict__ Cbf, float* __restrict__ Cf,
    const float* __restrict__ bias, const float* __restrict__ bias2,
    int M, int NZ, int NT, int MT, int zlin)
{
    __shared__ unsigned short As[2][128 * 32];
    __shared__ unsigned short Bs[2][128 * 32];

    int bi = blockIdx.x;
    int cx = bi & 7;
    int g = bi >> 3;
    int per = NZ * NT;
    int mh = g / per;
    int j  = g % per;
    int mt = mh * 8 + cx;
    if (mt >= MT) return;
    int z  = j % NZ;
    int nb = j / NZ;
    int m0 = mt * TM;
    int n0 = nb * TN;

    const unsigned short* Bz = Bt + ((size_t)z << 16);
    int t = threadIdx.x;
    int wave = t >> 6, lane = t & 63;
    int wr = wave >> 1, wc = wave & 1;
    int lrow = lane & 15, kq = lane >> 4;

    // staging: each wave DMAs 2x1024B chunks of As and Bs per K-step.
    // chunk q covers LDS rows [(wave*2+q)*16, +16); lane l -> row l>>2.
    // source col-group pre-swizzled: LDS[row][gp] = global[row][gp ^ ((row>>1)&3)]
    int sr0 = (wave * 2 + 0) * 16 + (lane >> 2);
    int sr1 = (wave * 2 + 1) * 16 + (lane >> 2);
    int sc = (((lane & 3) ^ ((lane >> 3) & 3))) * 8;
    int gm0 = m0 + sr0; if (gm0 >= M) gm0 = M - 1;  // clamp: dup rows never stored
    int gm1 = m0 + sr1; if (gm1 >= M) gm1 = M - 1;
    const unsigned short* gA0 = A + (size_t)gm0 * 256 + sc;
    const unsigned short* gA1 = A + (size_t)gm1 * 256 + sc;
    const unsigned short* gB0 = Bz + (size_t)(n0 + sr0) * 256 + sc;
    const unsigned short* gB1 = Bz + (size_t)(n0 + sr1) * 256 + sc;

    auto stage = [&](int b, int kt) {
        int ko = kt * 32;
        gl2l16(gA0 + ko, &As[b][(wave * 2 + 0) * 512]);
        gl2l16(gA1 + ko, &As[b][(wave * 2 + 1) * 512]);
        gl2l16(gB0 + ko, &Bs[b][(wave * 2 + 0) * 512]);
        gl2l16(gB1 + ko, &Bs[b][(wave * 2 + 1) * 512]);
    };

    // read-side swizzled K-group offset (elements)
    int rg = (kq ^ ((lrow >> 1) & 3)) * 8;

    f32x4 acc[4][4];
#pragma unroll
    for (int i = 0; i < 4; ++i)
#pragma unroll
        for (int jj = 0; jj < 4; ++jj) acc[i][jj] = (f32x4){0.f, 0.f, 0.f, 0.f};

    // prologue: 2-deep prefetch (8 loads outstanding)
    stage(0, 0);
    stage(1, 1);

    int cur = 0;
#pragma unroll 1
    for (int step = 0; step < 8; ++step) {
        // wait MY tile-step loads (newest 4 = tile step+1 stay in flight)
        if (step < 7) asm volatile("s_waitcnt vmcnt(4)" ::: "memory");
        else          asm volatile("s_waitcnt vmcnt(0)" ::: "memory");
        __builtin_amdgcn_s_barrier();          // publish: all waves' tile data in LDS
        __builtin_amdgcn_sched_barrier(0);

        short8 af[4], bf4[4];
#pragma unroll
        for (int i = 0; i < 4; ++i)
            af[i] = *(const short8*)(&As[cur][(wr * 64 + i * 16 + lrow) * 32 + rg]);
#pragma unroll
        for (int jj = 0; jj < 4; ++jj)
            bf4[jj] = *(const short8*)(&Bs[cur][(wc * 64 + jj * 16 + lrow) * 32 + rg]);
#pragma unroll
        for (int i = 0; i < 4; ++i)
#pragma unroll
            for (int jj = 0; jj < 4; ++jj)
                acc[i][jj] = __builtin_amdgcn_mfma_f32_16x16x32_bf16(bf4[jj], af[i],
                                                                     acc[i][jj], 0, 0, 0);
        __builtin_amdgcn_sched_barrier(0);     // pin reads/MFMAs before barrier2
        asm volatile("s_waitcnt lgkmcnt(0)" ::: "memory");  // ds_reads fully done
        __builtin_amdgcn_s_barrier();          // all waves done reading buf cur
        __builtin_amdgcn_sched_barrier(0);
        if (step < 6) stage(cur, step + 2);    // overwrite cur with tile step+2
        cur ^= 1;
    }

    // transposed D: each lane -> row gm = m0+wr*64+i*16+lrow,
    //               cols gnb..gnb+3 = n0+wc*64+jj*16+kq*4 ..
    if (z == zlin) {
#pragma unroll
        for (int i = 0; i < 4; ++i) {
            int gm = m0 + wr * 64 + i * 16 + lrow;
            if (gm >= M) continue;
#pragma unroll
            for (int jj = 0; jj < 4; ++jj) {
                int gnb = n0 + wc * 64 + jj * 16 + kq * 4;
                float4 b1 = *(const float4*)(bias + gnb);
                float4 b2 = *(const float4*)(bias2 + gnb);
                float4 v = {acc[i][jj][0] + b1.x + b2.x,
                            acc[i][jj][1] + b1.y + b2.y,
                            acc[i][jj][2] + b1.z + b2.z,
                            acc[i][jj][3] + b1.w + b2.w};
                *(float4*)(Cf + (size_t)gm * 256 + gnb) = v;
            }
        }
    } else {
#pragma unroll
        for (int i = 0; i < 4; ++i) {
            int gm = m0 + wr * 64 + i * 16 + lrow;
            if (gm >= M) continue;
#pragma unroll
            for (int jj = 0; jj < 4; ++jj) {
                int gnb = n0 + wc * 64 + jj * 16 + kq * 4;
                us4 v = {f2bf(acc[i][jj][0]), f2bf(acc[i][jj][1]),
                         f2bf(acc[i][jj][2]), f2bf(acc[i][jj][3])};
                *(us4*)(Cbf + ((size_t)z * M + gm) * 256 + gnb) = v;
            }
        }
    }
}

// ---------------- message aggregation: 2 waves per node, LDS combine ----------
// Block 256 thr = 4 waves = 2 nodes; wave parity p handles edges beg+p, beg+p+2, ...
__global__ __launch_bounds__(256) void k_msg_gather(
    const int* __restrict__ rowptr, const int* __restrict__ csr_se,
    const float* __restrict__ alpha_csr, const unsigned short* __restrict__ xw,
    const float* __restrict__ bias, float* __restrict__ out,
    unsigned short* __restrict__ xbout, int r0, int r1, int first, int act) {
    __shared__ float Pf[2][256];
    int tid = threadIdx.x;
    int wave = tid >> 6, lane = tid & 63;
    int nslot = wave >> 1, p = wave & 1;
    int node = blockIdx.x * 2 + nslot;
    int hsel = lane >> 4;
    float ax = 0.f, ay = 0.f, az = 0.f, aw = 0.f;

    auto edge = [&](int i) {
        int se = csr_se[i];
        int tt = se >> 16;
        if (tt >= r0 && tt < r1) {
            int s = se & 0xFFFF;
            float a = alpha_csr[i * 4 + hsel];
            uint2 pv = *(const uint2*)(xw + ((size_t)(tt - r0) * N + s) * 256 + lane * 4);
            ax += a * __uint_as_float(pv.x << 16);
            ay += a * __uint_as_float(pv.x & 0xFFFF0000u);
            az += a * __uint_as_float(pv.y << 16);
            aw += a * __uint_as_float(pv.y & 0xFFFF0000u);
        }
    };

    if (node < N) {
        int beg = rowptr[node], end = rowptr[node + 1];
        int i = beg + p;
        for (; i + 2 < end; i += 4) { edge(i); edge(i + 2); }
        if (i < end) edge(i);
    }
    if (p == 1) {
        float4 v = {ax, ay, az, aw};
        *(float4*)(&Pf[nslot][lane * 4]) = v;
    }
    __syncthreads();
    if (p == 0 && node < N) {
        float4 q = *(const float4*)(&Pf[nslot][lane * 4]);
        ax += q.x; ay += q.y; az += q.z; aw += q.w;
        float* o = out + (size_t)node * 256 + lane * 4;
        float vx, vy, vz, vw;
        if (first) {
            const float4 b = ((const float4*)bias)[lane];
            vx = ax + b.x; vy = ay + b.y; vz = az + b.z; vw = aw + b.w;
        } else {
            vx = o[0] + ax; vy = o[1] + ay; vz = o[2] + az; vw = o[3] + aw;
        }
        if (act) {
            vx = lrelu(vx, 0.01f); vy = lrelu(vy, 0.01f);
            vz = lrelu(vz, 0.01f); vw = lrelu(vw, 0.01f);
            unsigned short* xo = xbout + (size_t)node * 256 + lane * 4;
            xo[0] = f2bf(vx); xo[1] = f2bf(vy); xo[2] = f2bf(vz); xo[3] = f2bf(vw);
        }
        o[0] = vx; o[1] = vy; o[2] = vz; o[3] = vw;
    }
}

extern "C" void kernel_launch(void* const* d_in, const int* in_sizes, int n_in,
                              void* d_out, int out_size, void* d_ws, size_t ws_size,
                              hipStream_t stream) {
    const float* kg   = (const float*)d_in[0];
    const float* cc0  = (const float*)d_in[1];
    const float* gw1  = (const float*)d_in[2];
    const float* gb1  = (const float*)d_in[3];
    const float* gw2  = (const float*)d_in[4];
    const float* gb2  = (const float*)d_in[5];
    const float* r1w  = (const float*)d_in[6];
    const float* r1q  = (const float*)d_in[7];
    const float* r1k  = (const float*)d_in[8];
    const float* r1b  = (const float*)d_in[9];
    const float* r2w  = (const float*)d_in[10];
    const float* r2q  = (const float*)d_in[11];
    const float* r2k  = (const float*)d_in[12];
    const float* r2b  = (const float*)d_in[13];
    const float* linw = (const float*)d_in[14];
    const float* linb = (const float*)d_in[15];
    const int*   ei   = (const int*)d_in[16];
    const int*   et   = (const int*)d_in[17];

    float* out = (float*)d_out;
    float* a1  = out + (size_t)N * C;
    float* a2  = a1 + (size_t)E * H;

    float* ws = (float*)d_ws;
    size_t off = 0;
    float* dis  = ws + off; off += N;
    float* h1   = ws + off; off += (size_t)N * 32;
    float* c1   = ws + off; off += (size_t)N * 32;
    unsigned short* h2b = (unsigned short*)(ws + off); off += (size_t)N * 64;
    float* x0   = ws + off; off += (size_t)N * C;
    float* hmid = ws + off; off += (size_t)N * C;
    float* qn   = ws + off; off += (size_t)N * R * H;
    float* kn   = ws + off; off += (size_t)N * R * H;
    int* cnt     = (int*)(ws + off); off += N;
    int* rowptr  = (int*)(ws + off); off += N + 1;
    int* cursor  = (int*)(ws + off); off += N;
    int* csr_se  = (int*)(ws + off); off += E;
    int* csr_eid = (int*)(ws + off); off += E;
    float* alpha = ws + off; off += (size_t)E * H;
    unsigned short* xb0 = (unsigned short*)(ws + off); off += (size_t)N * 128;
    unsigned short* xb1 = (unsigned short*)(ws + off); off += (size_t)N * 128;
    // wt[0..R-1] = RGAT weights (transposed bf16); wt[R] = lin weight -> contiguous
    unsigned short* wt  = (unsigned short*)(ws + off); off += (size_t)(R + 1) * 32768;
    unsigned short* wtl = wt + ((size_t)R << 16);
    unsigned short* wqkb = (unsigned short*)(ws + off); off += 8192;
    unsigned short* xwb = (unsigned short*)(ws + off);

    size_t fixedB = off * 4;
    int K = R;
    if (ws_size > fixedB) {
        size_t kmax = (ws_size - fixedB) / ((size_t)N * C * 2);
        if (kmax < (size_t)K) K = (int)kmax;
    } else {
        K = 1;
    }
    if (K < 1) K = 1;

    const int B = 256;
    auto cdiv = [](long a, long b) { return (int)((a + b - 1) / b); };
    const int MT = cdiv(N, TM);  // 157 m-tiles
    const int NT = C / TN;       // 2

    // ---- CSR build ----
    k_zero_int<<<cdiv(N, B), B, 0, stream>>>(cnt, N);
    k_count<<<cdiv(E, B), B, 0, stream>>>(ei, cnt);
    k_scan<<<1, 1024, 0, stream>>>(cnt, rowptr, cursor, dis);
    k_scatter<<<cdiv(E, B), B, 0, stream>>>(ei, et, cursor, csr_se, csr_eid);

    // ---- GCN ----
    k_h1<<<cdiv((long)N * 32, B), B, 0, stream>>>(cc0, gw1, h1);
    k_agg32<<<cdiv((long)N * 32, B), B, 0, stream>>>(rowptr, csr_se, dis, h1, gb1, c1);
    k_h2kg<<<cdiv((long)N * 128, B), B, 0, stream>>>(c1, gw2, kg, h2b, x0, xb0);
    k_agg128<<<cdiv((long)N * 128, B), B, 0, stream>>>(rowptr, csr_se, dis, h2b,
                                                       gb2, x0, xb0);

    auto rgat = [&](unsigned short* xb, const float* W,
                    const float* q, const float* kk, const float* b,
                    float* obuf, unsigned short* xbout, float* aout,
                    int first, int act, int lin, float* linout,
                    const float* lb1, const float* lb2) {
        k_wqkb<<<512, 256, 0, stream>>>(W, q, kk, wqkb);
        k_qnkn_mfma<<<cdiv(N, 64), B, 0, stream>>>(xb, wqkb, qn, kn);
        k_soft<<<cdiv((long)N * 64, B), B, 0, stream>>>(rowptr, csr_se, csr_eid,
                                                        qn, kn, alpha, aout);
        k_wconv_t<<<R * 16, 256, 0, stream>>>(W, wt);
        for (int r0 = 0; r0 < R; r0 += K) {
            int kc = (R - r0) < K ? (R - r0) : K;
            int addlin = (lin && (r0 + kc == R)) ? 1 : 0;
            int nz = kc + addlin;
            int zl = addlin ? kc : -1;
            int gx = 8 * nz * NT * cdiv(MT, 8);
            gemm_mfma4<<<gx, 256, 0, stream>>>(xb, wt + ((size_t)r0 << 16), xwb,
                                               linout, lb1, lb2,
                                               N, nz, NT, MT, zl);
            int last = (r0 + kc >= R) ? 1 : 0;
            k_msg_gather<<<cdiv(N, 2), 256, 0, stream>>>(
                rowptr, csr_se, alpha, xwb, b, obuf, xbout, r0, r0 + kc,
                (first && r0 == 0) ? 1 : 0, act && last);
        }
    };

    // residual-linear weight transposed into wt[R] before layer 1
    k_wconv_t<<<16, 256, 0, stream>>>(linw, wtl);

    // layer 1: hmid = r1b + messages (leaky fused, emits xb1 bf16);
    //          merged z=8 slice writes out = x0@linw + (linb + r2b)
    rgat(xb0, r1w, r1q, r1k, r1b, hmid, xb1, a1, 1, 1,
         1, out, linb, r2b);

    // layer 2: out += messages (bias already folded into linear epilogue)
    rgat(xb1, r2w, r2q, r2k, r2b, out, nullptr, a2, 0, 0,
         0, nullptr, nullptr, nullptr);
}

// Round 5
// 518.946 us; speedup vs baseline: 1.0195x; 1.0109x over previous
//
#include <hip/hip_runtime.h>
#include <cstdint>

static constexpr int N = 20000;
static constexpr int E = 320000;
static constexpr int R = 8;
static constexpr int H = 4;
static constexpr int C = 256;

using short8 = __attribute__((ext_vector_type(8))) short;
using f32x4  = __attribute__((ext_vector_type(4))) float;
using us4    = __attribute__((ext_vector_type(4))) unsigned short;

__device__ __forceinline__ float lrelu(float x, float s) { return x >= 0.f ? x : s * x; }
__device__ __forceinline__ unsigned short f2bf(float f) {
    unsigned u = __float_as_uint(f);
    unsigned r = (u + 0x7FFFu + ((u >> 16) & 1u)) >> 16;
    return (unsigned short)r;
}
__device__ __forceinline__ float bf2f(unsigned short s) {
    return __uint_as_float(((unsigned)s) << 16);
}

// async global->LDS DMA, 16B per lane; LDS dest is wave-uniform base + lane*16
__device__ __forceinline__ void gl2l16(const unsigned short* g, unsigned short* l) {
    __builtin_amdgcn_global_load_lds(
        (const __attribute__((address_space(1))) unsigned int*)g,
        (__attribute__((address_space(3))) unsigned int*)l, 16, 0, 0);
}

// ---------------- CSR build ----------------
__global__ void k_zero_int(int* p, int n) {
    int i = blockIdx.x * blockDim.x + threadIdx.x;
    if (i < n) p[i] = 0;
}

__global__ void k_count(const int* __restrict__ ei, int* __restrict__ cnt) {
    int e = blockIdx.x * blockDim.x + threadIdx.x;
    if (e < E) atomicAdd(&cnt[ei[E + e]], 1);
}

// exclusive scan of cnt -> rowptr; also emits cursor copy and dis = rsqrt(cnt+1)
__global__ __launch_bounds__(1024) void k_scan(const int* __restrict__ cnt,
                                               int* __restrict__ rowptr,
                                               int* __restrict__ cursor,
                                               float* __restrict__ dis) {
    __shared__ int part[1024];
    const int CH = (N + 1023) / 1024;  // 20
    int t = threadIdx.x;
    int base = t * CH;
    int sum = 0;
    for (int j = 0; j < CH; ++j) {
        int idx = base + j;
        if (idx < N) sum += cnt[idx];
    }
    part[t] = sum;
    __syncthreads();
    for (int off = 1; off < 1024; off <<= 1) {
        int v = 0;
        if (t >= off) v = part[t - off];
        __syncthreads();
        if (t >= off) part[t] += v;
        __syncthreads();
    }
    int run = part[t] - sum;
    for (int j = 0; j < CH; ++j) {
        int idx = base + j;
        if (idx < N) {
            int cv = cnt[idx];
            rowptr[idx] = run;
            cursor[idx] = run;
            dis[idx] = rsqrtf((float)cv + 1.0f);
            run += cv;
        }
    }
    if (t == 1023) rowptr[N] = part[1023];
}

// csr_se packs (edge_type<<16)|src ; csr_eid keeps original edge id
__global__ void k_scatter(const int* __restrict__ ei, const int* __restrict__ et,
                          int* __restrict__ cursor, int* __restrict__ csr_se,
                          int* __restrict__ csr_eid) {
    int e = blockIdx.x * blockDim.x + threadIdx.x;
    if (e >= E) return;
    int d = ei[E + e];
    int pos = atomicAdd(&cursor[d], 1);
    csr_se[pos] = (et[e] << 16) | ei[e];
    csr_eid[pos] = e;
}

// ---------------- GCN ----------------
__global__ void k_h1(const float* __restrict__ x, const float* __restrict__ W,
                     float* __restrict__ h) {
    int idx = blockIdx.x * blockDim.x + threadIdx.x;
    if (idx >= N * 32) return;
    int n = idx >> 5, f = idx & 31;
    const float* xr = x + n * 4;
    float acc = 0.f;
#pragma unroll
    for (int c = 0; c < 4; ++c) acc += xr[c] * W[c * 32 + f];
    h[idx] = acc;
}

__global__ void k_agg32(const int* __restrict__ rowptr, const int* __restrict__ csr_se,
                        const float* __restrict__ dis, const float* __restrict__ h,
                        const float* __restrict__ b, float* __restrict__ c) {
    int idx = blockIdx.x * blockDim.x + threadIdx.x;
    if (idx >= N * 32) return;
    int d = idx >> 5, f = idx & 31;
    int beg = rowptr[d], end = rowptr[d + 1];
    float acc = 0.f;
    for (int i = beg; i < end; ++i) {
        int s = csr_se[i] & 0xFFFF;
        acc += dis[s] * h[s * 32 + f];
    }
    float dd = dis[d];
    c[idx] = dd * acc + dd * dd * h[idx] + b[f];
}

// h2 (bf16) + kg copy into x0/xb0, one dispatch
__global__ void k_h2kg(const float* __restrict__ c1, const float* __restrict__ W,
                       const float* __restrict__ kg, unsigned short* __restrict__ h,
                       float* __restrict__ x0, unsigned short* __restrict__ xb0) {
    int idx = blockIdx.x * blockDim.x + threadIdx.x;
    if (idx >= N * 128) return;
    int n = idx >> 7, f = idx & 127;
    const float* cr = c1 + n * 32;
    float acc = 0.f;
    for (int c = 0; c < 32; ++c) acc += lrelu(cr[c], 0.01f) * W[c * 128 + f];
    h[idx] = f2bf(acc);
    float v = kg[idx];
    x0[n * 256 + f] = v;
    xb0[n * 256 + f] = f2bf(v);
}

__global__ void k_agg128(const int* __restrict__ rowptr, const int* __restrict__ csr_se,
                         const float* __restrict__ dis,
                         const unsigned short* __restrict__ h,
                         const float* __restrict__ b, float* __restrict__ x0,
                         unsigned short* __restrict__ xb0) {
    int idx = blockIdx.x * blockDim.x + threadIdx.x;
    if (idx >= N * 128) return;
    int d = idx >> 7, f = idx & 127;
    int beg = rowptr[d], end = rowptr[d + 1];
    float acc = 0.f;
    int i = beg;
    for (; i + 2 <= end; i += 2) {
        int s0 = csr_se[i] & 0xFFFF;
        int s1 = csr_se[i + 1] & 0xFFFF;
        float d0 = dis[s0], d1 = dis[s1];
        float v0 = bf2f(h[s0 * 128 + f]), v1 = bf2f(h[s1 * 128 + f]);
        acc += d0 * v0 + d1 * v1;
    }
    if (i < end) {
        int s = csr_se[i] & 0xFFFF;
        acc += dis[s] * bf2f(h[s * 128 + f]);
    }
    float dd = dis[d];
    float v = dd * acc + dd * dd * bf2f(h[d * 128 + f]) + b[f];
    x0[d * 256 + 128 + f] = v;
    xb0[d * 256 + 128 + f] = f2bf(v);
}

// ---------------- RGAT attention ----------------
// wave-per-(r,i) W@q / W@k projection: coalesced row read + shuffle reduce.
// wqkb[n][k]: n<32 -> q proj (n = r*4+h), n>=32 -> k proj (n = 32+r*4+h)
__global__ __launch_bounds__(256) void k_wqkb(const float* __restrict__ W,
                                              const float* __restrict__ q,
                                              const float* __restrict__ kmat,
                                              unsigned short* __restrict__ wqkb) {
    int w = (blockIdx.x * blockDim.x + threadIdx.x) >> 6;  // 0..2047
    int lane = threadIdx.x & 63;
    int r = w >> 8, i = w & 255;
    const float* wr = W + ((size_t)(r * 256 + i)) * 256;
    float4 a = *(const float4*)(wr + lane * 4);
    float aq0 = 0.f, aq1 = 0.f, aq2 = 0.f, aq3 = 0.f;
    float ak0 = 0.f, ak1 = 0.f, ak2 = 0.f, ak3 = 0.f;
    int o = lane * 4;
    const float av[4] = {a.x, a.y, a.z, a.w};
#pragma unroll
    for (int j = 0; j < 4; ++j) {
        float4 qv = *(const float4*)(q + (o + j) * 4);
        float4 kv = *(const float4*)(kmat + (o + j) * 4);
        aq0 += av[j] * qv.x; aq1 += av[j] * qv.y;
        aq2 += av[j] * qv.z; aq3 += av[j] * qv.w;
        ak0 += av[j] * kv.x; ak1 += av[j] * kv.y;
        ak2 += av[j] * kv.z; ak3 += av[j] * kv.w;
    }
#pragma unroll
    for (int d = 1; d < 64; d <<= 1) {
        aq0 += __shfl_xor(aq0, d); aq1 += __shfl_xor(aq1, d);
        aq2 += __shfl_xor(aq2, d); aq3 += __shfl_xor(aq3, d);
        ak0 += __shfl_xor(ak0, d); ak1 += __shfl_xor(ak1, d);
        ak2 += __shfl_xor(ak2, d); ak3 += __shfl_xor(ak3, d);
    }
    if (lane == 0) {
        int nq = r * 4, nk = 32 + r * 4;
        wqkb[(nq + 0) * 256 + i] = f2bf(aq0);
        wqkb[(nq + 1) * 256 + i] = f2bf(aq1);
        wqkb[(nq + 2) * 256 + i] = f2bf(aq2);
        wqkb[(nq + 3) * 256 + i] = f2bf(aq3);
        wqkb[(nk + 0) * 256 + i] = f2bf(ak0);
        wqkb[(nk + 1) * 256 + i] = f2bf(ak1);
        wqkb[(nk + 2) * 256 + i] = f2bf(ak2);
        wqkb[(nk + 3) * 256 + i] = f2bf(ak3);
    }
}

// qn|kn = xb @ wqkb^T via MFMA.  Block: 256 thr = 4 waves, 64 rows per block.
// Operands SWAPPED (mfma(b,a,acc) computes C^T): D-row = output col (kq*4+reg),
// D-col = node row (lrow) -> each lane holds 4 consecutive cols of one node row
// -> float4 stores.
#define QP 264
__global__ __launch_bounds__(256) void k_qnkn_mfma(
    const unsigned short* __restrict__ xb, const unsigned short* __restrict__ wqkb,
    float* __restrict__ qn, float* __restrict__ kn)
{
    __shared__ unsigned short Ws[64 * QP];
    int t = threadIdx.x;
    {
        int r = t >> 2, off = (t & 3) * 64;
#pragma unroll
        for (int i = 0; i < 8; ++i)
            *(uint4*)(&Ws[r * QP + off + i * 8]) =
                *(const uint4*)(wqkb + r * 256 + off + i * 8);
    }
    __syncthreads();
    int wave = t >> 6, lane = t & 63;
    int lrow = lane & 15, kq = lane >> 4;
    int mw = blockIdx.x * 64 + wave * 16;
    int gm = mw + lrow;
    int gmc = gm < N ? gm : N - 1;

    f32x4 acc[4];
#pragma unroll
    for (int j = 0; j < 4; ++j) acc[j] = (f32x4){0.f, 0.f, 0.f, 0.f};

    for (int k0 = 0; k0 < 8; ++k0) {
        short8 af = *(const short8*)(xb + (size_t)gmc * 256 + k0 * 32 + kq * 8);
#pragma unroll
        for (int j = 0; j < 4; ++j) {
            short8 bf4 = *(const short8*)(&Ws[(j * 16 + lrow) * QP + k0 * 32 + kq * 8]);
            acc[j] = __builtin_amdgcn_mfma_f32_16x16x32_bf16(bf4, af, acc[j], 0, 0, 0);
        }
    }
    if (gm < N) {
#pragma unroll
        for (int j = 0; j < 4; ++j) {
            int colb = j * 16 + kq * 4;
            float4 v = {acc[j][0], acc[j][1], acc[j][2], acc[j][3]};
            if (colb < 32) *(float4*)(qn + (size_t)gm * 32 + colb) = v;
            else           *(float4*)(kn + (size_t)gm * 32 + (colb - 32)) = v;
        }
    }
}

// wave-per-node softmax: lanes = 16 edge-slots x 4 heads, shuffle reductions.
__global__ void k_soft(const int* __restrict__ rowptr, const int* __restrict__ csr_se,
                       const int* __restrict__ csr_eid,
                       const float* __restrict__ qn, const float* __restrict__ kn,
                       float* __restrict__ alpha_csr, float* __restrict__ aout) {
    int wid = (blockIdx.x * blockDim.x + threadIdx.x) >> 6;
    int lane = threadIdx.x & 63;
    if (wid >= N) return;
    int d = wid;
    int beg = rowptr[d], end = rowptr[d + 1];
    if (beg >= end) return;
    int slot = lane >> 2, h = lane & 3;
    int nc = (end - beg + 15) >> 4;
    const float* qrow = qn + d * 32;

    auto rawv = [&](int i) {
        int se = csr_se[i];
        int tt = se >> 16, s = se & 0xFFFF;
        return lrelu(qrow[tt * 4 + h] + kn[s * 32 + tt * 4 + h], 0.2f);
    };

    float av[4];
    float m = -1e30f;
    for (int c = 0; c < nc; ++c) {
        int i = beg + c * 16 + slot;
        float v = (i < end) ? rawv(i) : -1e30f;
        if (c < 4) av[c] = v;
        m = fmaxf(m, v);
    }
    m = fmaxf(m, __shfl_xor(m, 4));
    m = fmaxf(m, __shfl_xor(m, 8));
    m = fmaxf(m, __shfl_xor(m, 16));
    m = fmaxf(m, __shfl_xor(m, 32));

    float sum = 0.f;
    for (int c = 0; c < nc; ++c) {
        int i = beg + c * 16 + slot;
        float ex = 0.f;
        if (i < end) {
            float v = (c < 4) ? av[c] : rawv(i);
            ex = expf(v - m);
        }
        if (c < 4) av[c] = ex;
        sum += ex;
    }
    sum += __shfl_xor(sum, 4);
    sum += __shfl_xor(sum, 8);
    sum += __shfl_xor(sum, 16);
    sum += __shfl_xor(sum, 32);
    float inv = 1.f / sum;

    for (int c = 0; c < nc; ++c) {
        int i = beg + c * 16 + slot;
        if (i < end) {
            float ex = (c < 4) ? av[c] : expf(rawv(i) - m);
            float a = ex * inv;
            alpha_csr[i * 4 + h] = a;
            aout[csr_eid[i] * 4 + h] = a;
        }
    }
}

// Wt[z][n][k] = bf16(W[z][k][n])  -- 64x64 LDS-tile transpose, coalesced both ways
#define WTP 72
__global__ __launch_bounds__(256) void k_wconv_t(const float* __restrict__ W,
                                                 unsigned short* __restrict__ Wt) {
    int bid = blockIdx.x;
    int z = bid >> 4;
    int tile = bid & 15;
    int k0 = (tile >> 2) * 64, n0 = (tile & 3) * 64;
    __shared__ unsigned short T[64 * WTP];
    int t = threadIdx.x;
    const float* Wz = W + ((size_t)z << 16);
    int r = t >> 4;
    int cs = (t & 15) * 4;
#pragma unroll
    for (int rr = 0; rr < 4; ++rr) {
        int k = r + rr * 16;
        float4 v = *(const float4*)(Wz + (size_t)(k0 + k) * 256 + n0 + cs);
        T[(cs + 0) * WTP + k] = f2bf(v.x);
        T[(cs + 1) * WTP + k] = f2bf(v.y);
        T[(cs + 2) * WTP + k] = f2bf(v.z);
        T[(cs + 3) * WTP + k] = f2bf(v.w);
    }
    __syncthreads();
    int n = t >> 2, ck = (t & 3) * 16;
    unsigned short* dst = Wt + ((size_t)z << 16) + (size_t)(n0 + n) * 256 + k0 + ck;
    const unsigned short* srcp = T + n * WTP + ck;
    *(uint4*)(dst) = *(const uint4*)(srcp);
    *(uint4*)(dst + 8) = *(const uint4*)(srcp + 8);
}

// ---------------- bf16 MFMA GEMM: m97 structure + swizzle + C^T epilogue -------
// (round-3 core, proven; now M-SPLIT: MTd tiles starting at tile mt0, so the
//  bench's top-5 surfaces the largest non-gemm dispatch -> visibility probe)
#define TM 128
#define TN 128
__global__ __launch_bounds__(256) void gemm_mfma4(
    const unsigned short* __restrict__ A, const unsigned short* __restrict__ Bt,
    unsigned short* __restrict__ Cbf, float* __restrict__ Cf,
    const float* __restrict__ bias, const float* __restrict__ bias2,
    int M, int NZ, int NT, int MTd, int mt0, int zlin)
{
    __shared__ unsigned short As[128 * 32];
    __shared__ unsigned short Bs[128 * 32];

    int bi = blockIdx.x;
    int cx = bi & 7;
    int g = bi >> 3;
    int per = NZ * NT;
    int mh = g / per;
    int j  = g % per;
    int mtl = mh * 8 + cx;
    if (mtl >= MTd) return;
    int mt = mt0 + mtl;
    int z  = j % NZ;
    int nb = j / NZ;
    int m0 = mt * TM;
    int n0 = nb * TN;

    const unsigned short* Bz = Bt + ((size_t)z << 16);
    int t = threadIdx.x;
    int wave = t >> 6, lane = t & 63;
    int wr = wave >> 1, wc = wave & 1;
    int lrow = lane & 15, kq = lane >> 4;

    // staging: source col-group pre-swizzled: LDS[row][gp]=global[row][gp^((row>>1)&3)]
    int sr0 = (wave * 2 + 0) * 16 + (lane >> 2);
    int sr1 = (wave * 2 + 1) * 16 + (lane >> 2);
    int sc = (((lane & 3) ^ ((lane >> 3) & 3))) * 8;
    int gm0 = m0 + sr0; if (gm0 >= M) gm0 = M - 1;  // clamp: dup rows never stored
    int gm1 = m0 + sr1; if (gm1 >= M) gm1 = M - 1;
    const unsigned short* gA0 = A + (size_t)gm0 * 256 + sc;
    const unsigned short* gA1 = A + (size_t)gm1 * 256 + sc;
    const unsigned short* gB0 = Bz + (size_t)(n0 + sr0) * 256 + sc;
    const unsigned short* gB1 = Bz + (size_t)(n0 + sr1) * 256 + sc;
    unsigned short* lA0 = &As[(wave * 2 + 0) * 512];
    unsigned short* lA1 = &As[(wave * 2 + 1) * 512];
    unsigned short* lB0 = &Bs[(wave * 2 + 0) * 512];
    unsigned short* lB1 = &Bs[(wave * 2 + 1) * 512];

    // read-side swizzled K-group offset (elements)
    int rg = (kq ^ ((lrow >> 1) & 3)) * 8;

    f32x4 acc[4][4];
#pragma unroll
    for (int i = 0; i < 4; ++i)
#pragma unroll
        for (int jj = 0; jj < 4; ++jj) acc[i][jj] = (f32x4){0.f, 0.f, 0.f, 0.f};

    for (int k0 = 0; k0 < 256; k0 += 32) {
        gl2l16(gA0 + k0, lA0);
        gl2l16(gA1 + k0, lA1);
        gl2l16(gB0 + k0, lB0);
        gl2l16(gB1 + k0, lB1);
        __syncthreads();   // drains vmcnt(0) before barrier
        short8 af[4], bf4[4];
#pragma unroll
        for (int i = 0; i < 4; ++i)
            af[i] = *(const short8*)(&As[(wr * 64 + i * 16 + lrow) * 32 + rg]);
#pragma unroll
        for (int jj = 0; jj < 4; ++jj)
            bf4[jj] = *(const short8*)(&Bs[(wc * 64 + jj * 16 + lrow) * 32 + rg]);
#pragma unroll
        for (int i = 0; i < 4; ++i)
#pragma unroll
            for (int jj = 0; jj < 4; ++jj)
                acc[i][jj] = __builtin_amdgcn_mfma_f32_16x16x32_bf16(bf4[jj], af[i],
                                                                     acc[i][jj], 0, 0, 0);
        __syncthreads();
    }
    // transposed D: each lane -> row gm = m0+wr*64+i*16+lrow,
    //               cols gnb..gnb+3 = n0+wc*64+jj*16+kq*4 ..
    if (z == zlin) {
#pragma unroll
        for (int i = 0; i < 4; ++i) {
            int gm = m0 + wr * 64 + i * 16 + lrow;
            if (gm >= M) continue;
#pragma unroll
            for (int jj = 0; jj < 4; ++jj) {
                int gnb = n0 + wc * 64 + jj * 16 + kq * 4;
                float4 b1 = *(const float4*)(bias + gnb);
                float4 b2 = *(const float4*)(bias2 + gnb);
                float4 v = {acc[i][jj][0] + b1.x + b2.x,
                            acc[i][jj][1] + b1.y + b2.y,
                            acc[i][jj][2] + b1.z + b2.z,
                            acc[i][jj][3] + b1.w + b2.w};
                *(float4*)(Cf + (size_t)gm * 256 + gnb) = v;
            }
        }
    } else {
#pragma unroll
        for (int i = 0; i < 4; ++i) {
            int gm = m0 + wr * 64 + i * 16 + lrow;
            if (gm >= M) continue;
#pragma unroll
            for (int jj = 0; jj < 4; ++jj) {
                int gnb = n0 + wc * 64 + jj * 16 + kq * 4;
                us4 v = {f2bf(acc[i][jj][0]), f2bf(acc[i][jj][1]),
                         f2bf(acc[i][jj][2]), f2bf(acc[i][jj][3])};
                *(us4*)(Cbf + ((size_t)z * M + gm) * 256 + gnb) = v;
            }
        }
    }
}

// ---------------- message aggregation: 1 wave per node, 4-deep edge pipeline ---
// Block 256 thr = 4 waves = 4 independent nodes (no LDS combine, no barrier).
// Fast path (r0==0,r1==R): no per-edge relation check; 4 se + 4 alpha issued,
// then 4 xw row-loads in flight, then FMA-reduce.
__global__ __launch_bounds__(256) void k_msg_gather(
    const int* __restrict__ rowptr, const int* __restrict__ csr_se,
    const float* __restrict__ alpha_csr, const unsigned short* __restrict__ xw,
    const float* __restrict__ bias, float* __restrict__ out,
    unsigned short* __restrict__ xbout, int r0, int r1, int first, int act) {
    int node = blockIdx.x * 4 + (threadIdx.x >> 6);
    if (node >= N) return;
    int lane = threadIdx.x & 63;
    int hsel = lane >> 4;
    int beg = rowptr[node], end = rowptr[node + 1];
    float ax = 0.f, ay = 0.f, az = 0.f, aw = 0.f;
    const unsigned short* xwl = xw + lane * 4;

    auto accum = [&](int se, float a) {
        int tt = se >> 16, s = se & 0xFFFF;
        uint2 pv = *(const uint2*)(xwl + ((size_t)tt * N + s) * 256);
        ax += a * __uint_as_float(pv.x << 16);
        ay += a * __uint_as_float(pv.x & 0xFFFF0000u);
        az += a * __uint_as_float(pv.y << 16);
        aw += a * __uint_as_float(pv.y & 0xFFFF0000u);
    };

    if (r0 == 0 && r1 == R) {
        int i = beg;
        for (; i + 4 <= end; i += 4) {
            int se0 = csr_se[i], se1 = csr_se[i + 1];
            int se2 = csr_se[i + 2], se3 = csr_se[i + 3];
            float a0 = alpha_csr[i * 4 + hsel];
            float a1 = alpha_csr[i * 4 + 4 + hsel];
            float a2 = alpha_csr[i * 4 + 8 + hsel];
            float a3 = alpha_csr[i * 4 + 12 + hsel];
            accum(se0, a0); accum(se1, a1); accum(se2, a2); accum(se3, a3);
        }
        for (; i < end; ++i) accum(csr_se[i], alpha_csr[i * 4 + hsel]);
    } else {
        for (int i = beg; i < end; ++i) {
            int se = csr_se[i];
            int tt = se >> 16;
            if (tt >= r0 && tt < r1) {
                int s = se & 0xFFFF;
                float a = alpha_csr[i * 4 + hsel];
                uint2 pv = *(const uint2*)(xwl + ((size_t)(tt - r0) * N + s) * 256);
                ax += a * __uint_as_float(pv.x << 16);
                ay += a * __uint_as_float(pv.x & 0xFFFF0000u);
                az += a * __uint_as_float(pv.y << 16);
                aw += a * __uint_as_float(pv.y & 0xFFFF0000u);
            }
        }
    }

    float* o = out + (size_t)node * 256 + lane * 4;
    float vx, vy, vz, vw;
    if (first) {
        float4 b = *(const float4*)(bias + lane * 4);
        vx = ax + b.x; vy = ay + b.y; vz = az + b.z; vw = aw + b.w;
    } else {
        float4 q = *(const float4*)o;
        vx = q.x + ax; vy = q.y + ay; vz = q.z + az; vw = q.w + aw;
    }
    if (act) {
        vx = lrelu(vx, 0.01f); vy = lrelu(vy, 0.01f);
        vz = lrelu(vz, 0.01f); vw = lrelu(vw, 0.01f);
        us4 xv = {f2bf(vx), f2bf(vy), f2bf(vz), f2bf(vw)};
        *(us4*)(xbout + (size_t)node * 256 + lane * 4) = xv;
    }
    float4 v = {vx, vy, vz, vw};
    *(float4*)o = v;
}

extern "C" void kernel_launch(void* const* d_in, const int* in_sizes, int n_in,
                              void* d_out, int out_size, void* d_ws, size_t ws_size,
                              hipStream_t stream) {
    const float* kg   = (const float*)d_in[0];
    const float* cc0  = (const float*)d_in[1];
    const float* gw1  = (const float*)d_in[2];
    const float* gb1  = (const float*)d_in[3];
    const float* gw2  = (const float*)d_in[4];
    const float* gb2  = (const float*)d_in[5];
    const float* r1w  = (const float*)d_in[6];
    const float* r1q  = (const float*)d_in[7];
    const float* r1k  = (const float*)d_in[8];
    const float* r1b  = (const float*)d_in[9];
    const float* r2w  = (const float*)d_in[10];
    const float* r2q  = (const float*)d_in[11];
    const float* r2k  = (const float*)d_in[12];
    const float* r2b  = (const float*)d_in[13];
    const float* linw = (const float*)d_in[14];
    const float* linb = (const float*)d_in[15];
    const int*   ei   = (const int*)d_in[16];
    const int*   et   = (const int*)d_in[17];

    float* out = (float*)d_out;
    float* a1  = out + (size_t)N * C;
    float* a2  = a1 + (size_t)E * H;

    float* ws = (float*)d_ws;
    size_t off = 0;
    float* dis  = ws + off; off += N;
    float* h1   = ws + off; off += (size_t)N * 32;
    float* c1   = ws + off; off += (size_t)N * 32;
    unsigned short* h2b = (unsigned short*)(ws + off); off += (size_t)N * 64;
    float* x0   = ws + off; off += (size_t)N * C;
    float* hmid = ws + off; off += (size_t)N * C;
    float* qn   = ws + off; off += (size_t)N * R * H;
    float* kn   = ws + off; off += (size_t)N * R * H;
    int* cnt     = (int*)(ws + off); off += N;
    int* rowptr  = (int*)(ws + off); off += N + 1;
    int* cursor  = (int*)(ws + off); off += N;
    int* csr_se  = (int*)(ws + off); off += E;
    int* csr_eid = (int*)(ws + off); off += E;
    float* alpha = ws + off; off += (size_t)E * H;
    unsigned short* xb0 = (unsigned short*)(ws + off); off += (size_t)N * 128;
    unsigned short* xb1 = (unsigned short*)(ws + off); off += (size_t)N * 128;
    // wt[0..R-1] = RGAT weights (transposed bf16); wt[R] = lin weight -> contiguous
    unsigned short* wt  = (unsigned short*)(ws + off); off += (size_t)(R + 1) * 32768;
    unsigned short* wtl = wt + ((size_t)R << 16);
    unsigned short* wqkb = (unsigned short*)(ws + off); off += 8192;
    unsigned short* xwb = (unsigned short*)(ws + off);

    size_t fixedB = off * 4;
    int K = R;
    if (ws_size > fixedB) {
        size_t kmax = (ws_size - fixedB) / ((size_t)N * C * 2);
        if (kmax < (size_t)K) K = (int)kmax;
    } else {
        K = 1;
    }
    if (K < 1) K = 1;

    const int B = 256;
    auto cdiv = [](long a, long b) { return (int)((a + b - 1) / b); };
    const int MT = cdiv(N, TM);  // 157 m-tiles
    const int NT = C / TN;       // 2
    const int mtA = (MT + 1) / 2;    // 79
    const int mtB = MT - mtA;        // 78

    // ---- CSR build ----
    k_zero_int<<<cdiv(N, B), B, 0, stream>>>(cnt, N);
    k_count<<<cdiv(E, B), B, 0, stream>>>(ei, cnt);
    k_scan<<<1, 1024, 0, stream>>>(cnt, rowptr, cursor, dis);
    k_scatter<<<cdiv(E, B), B, 0, stream>>>(ei, et, cursor, csr_se, csr_eid);

    // ---- GCN ----
    k_h1<<<cdiv((long)N * 32, B), B, 0, stream>>>(cc0, gw1, h1);
    k_agg32<<<cdiv((long)N * 32, B), B, 0, stream>>>(rowptr, csr_se, dis, h1, gb1, c1);
    k_h2kg<<<cdiv((long)N * 128, B), B, 0, stream>>>(c1, gw2, kg, h2b, x0, xb0);
    k_agg128<<<cdiv((long)N * 128, B), B, 0, stream>>>(rowptr, csr_se, dis, h2b,
                                                       gb2, x0, xb0);

    auto rgat = [&](unsigned short* xb, const float* W,
                    const float* q, const float* kk, const float* b,
                    float* obuf, unsigned short* xbout, float* aout,
                    int first, int act, int lin, float* linout,
                    const float* lb1, const float* lb2) {
        k_wqkb<<<512, 256, 0, stream>>>(W, q, kk, wqkb);
        k_qnkn_mfma<<<cdiv(N, 64), B, 0, stream>>>(xb, wqkb, qn, kn);
        k_soft<<<cdiv((long)N * 64, B), B, 0, stream>>>(rowptr, csr_se, csr_eid,
                                                        qn, kn, alpha, aout);
        k_wconv_t<<<R * 16, 256, 0, stream>>>(W, wt);
        for (int r0 = 0; r0 < R; r0 += K) {
            int kc = (R - r0) < K ? (R - r0) : K;
            int addlin = (lin && (r0 + kc == R)) ? 1 : 0;
            int nz = kc + addlin;
            int zl = addlin ? kc : -1;
            int gx1 = 8 * nz * NT * cdiv(mtA, 8);
            gemm_mfma4<<<gx1, 256, 0, stream>>>(xb, wt + ((size_t)r0 << 16), xwb,
                                                linout, lb1, lb2,
                                                N, nz, NT, mtA, 0, zl);
            int gx2 = 8 * nz * NT * cdiv(mtB, 8);
            gemm_mfma4<<<gx2, 256, 0, stream>>>(xb, wt + ((size_t)r0 << 16), xwb,
                                                linout, lb1, lb2,
                                                N, nz, NT, mtB, mtA, zl);
            int last = (r0 + kc >= R) ? 1 : 0;
            k_msg_gather<<<cdiv(N, 4), 256, 0, stream>>>(
                rowptr, csr_se, alpha, xwb, b, obuf, xbout, r0, r0 + kc,
                (first && r0 == 0) ? 1 : 0, act && last);
        }
    };

    // residual-linear weight transposed into wt[R] before layer 1
    k_wconv_t<<<16, 256, 0, stream>>>(linw, wtl);

    // layer 1: hmid = r1b + messages (leaky fused, emits xb1 bf16);
    //          merged z=8 slice writes out = x0@linw + (linb + r2b)
    rgat(xb0, r1w, r1q, r1k, r1b, hmid, xb1, a1, 1, 1,
         1, out, linb, r2b);

    // layer 2: out += messages (bias already folded into linear epilogue)
    rgat(xb1, r2w, r2q, r2k, r2b, out, nullptr, a2, 0, 0,
         0, nullptr, nullptr, nullptr);
}

// Round 6
// 475.717 us; speedup vs baseline: 1.1121x; 1.0909x over previous
//
#include <hip/hip_runtime.h>
#include <cstdint>

static constexpr int N = 20000;
static constexpr int E = 320000;
static constexpr int R = 8;
static constexpr int H = 4;
static constexpr int C = 256;

using short8 = __attribute__((ext_vector_type(8))) short;
using f32x4  = __attribute__((ext_vector_type(4))) float;
using us4    = __attribute__((ext_vector_type(4))) unsigned short;

__device__ __forceinline__ float lrelu(float x, float s) { return x >= 0.f ? x : s * x; }
__device__ __forceinline__ unsigned short f2bf(float f) {
    unsigned u = __float_as_uint(f);
    unsigned r = (u + 0x7FFFu + ((u >> 16) & 1u)) >> 16;
    return (unsigned short)r;
}
__device__ __forceinline__ float bf2f(unsigned short s) {
    return __uint_as_float(((unsigned)s) << 16);
}

// async global->LDS DMA, 16B per lane; LDS dest is wave-uniform base + lane*16
__device__ __forceinline__ void gl2l16(const unsigned short* g, unsigned short* l) {
    __builtin_amdgcn_global_load_lds(
        (const __attribute__((address_space(1))) unsigned int*)g,
        (__attribute__((address_space(3))) unsigned int*)l, 16, 0, 0);
}

// ---------------- CSR build ----------------
__global__ void k_zero_int(int* p, int n) {
    int i = blockIdx.x * blockDim.x + threadIdx.x;
    if (i < n) p[i] = 0;
}

__global__ void k_count(const int* __restrict__ ei, int* __restrict__ cnt) {
    int e = blockIdx.x * blockDim.x + threadIdx.x;
    if (e < E) atomicAdd(&cnt[ei[E + e]], 1);
}

// ---- parallel 3-phase scan (replaces single-block k_scan: 47.7us -> ~8us) ----
// A: per-block (256 elems) scan -> exclusive local prefix + block total
__global__ __launch_bounds__(256) void k_scan_a(const int* __restrict__ cnt,
                                                int* __restrict__ loc,
                                                int* __restrict__ bsum) {
    __shared__ int sm[256];
    int t = threadIdx.x;
    int idx = blockIdx.x * 256 + t;
    int v = (idx < N) ? cnt[idx] : 0;
    sm[t] = v;
    __syncthreads();
#pragma unroll
    for (int off = 1; off < 256; off <<= 1) {
        int u = (t >= off) ? sm[t - off] : 0;
        __syncthreads();
        if (t >= off) sm[t] += u;
        __syncthreads();
    }
    if (idx < N) loc[idx] = sm[t] - v;
    if (t == 255) bsum[blockIdx.x] = sm[255];
}

// B: exclusive scan of block totals (nb <= 256), single tiny block
__global__ __launch_bounds__(256) void k_scan_b(int* __restrict__ bsum, int nb) {
    __shared__ int sm[256];
    int t = threadIdx.x;
    int v = (t < nb) ? bsum[t] : 0;
    sm[t] = v;
    __syncthreads();
#pragma unroll
    for (int off = 1; off < 256; off <<= 1) {
        int u = (t >= off) ? sm[t - off] : 0;
        __syncthreads();
        if (t >= off) sm[t] += u;
        __syncthreads();
    }
    if (t < nb) bsum[t] = sm[t] - v;
}

// C: combine -> rowptr/cursor/dis; rowptr[N] = E (known: every edge has a dst)
__global__ __launch_bounds__(256) void k_scan_c(const int* __restrict__ cnt,
                                                const int* __restrict__ loc,
                                                const int* __restrict__ bsum,
                                                int* __restrict__ rowptr,
                                                int* __restrict__ cursor,
                                                float* __restrict__ dis) {
    int idx = blockIdx.x * 256 + threadIdx.x;
    if (idx == 0) rowptr[N] = E;
    if (idx >= N) return;
    int run = bsum[blockIdx.x] + loc[idx];
    rowptr[idx] = run;
    cursor[idx] = run;
    dis[idx] = rsqrtf((float)cnt[idx] + 1.0f);
}

// csr_se packs (edge_type<<16)|src ; csr_eid keeps original edge id
__global__ void k_scatter(const int* __restrict__ ei, const int* __restrict__ et,
                          int* __restrict__ cursor, int* __restrict__ csr_se,
                          int* __restrict__ csr_eid) {
    int e = blockIdx.x * blockDim.x + threadIdx.x;
    if (e >= E) return;
    int d = ei[E + e];
    int pos = atomicAdd(&cursor[d], 1);
    csr_se[pos] = (et[e] << 16) | ei[e];
    csr_eid[pos] = e;
}

// ---------------- GCN ----------------
__global__ void k_h1(const float* __restrict__ x, const float* __restrict__ W,
                     float* __restrict__ h) {
    int idx = blockIdx.x * blockDim.x + threadIdx.x;
    if (idx >= N * 32) return;
    int n = idx >> 5, f = idx & 31;
    const float* xr = x + n * 4;
    float acc = 0.f;
#pragma unroll
    for (int c = 0; c < 4; ++c) acc += xr[c] * W[c * 32 + f];
    h[idx] = acc;
}

__global__ void k_agg32(const int* __restrict__ rowptr, const int* __restrict__ csr_se,
                        const float* __restrict__ dis, const float* __restrict__ h,
                        const float* __restrict__ b, float* __restrict__ c) {
    int idx = blockIdx.x * blockDim.x + threadIdx.x;
    if (idx >= N * 32) return;
    int d = idx >> 5, f = idx & 31;
    int beg = rowptr[d], end = rowptr[d + 1];
    float acc = 0.f;
    for (int i = beg; i < end; ++i) {
        int s = csr_se[i] & 0xFFFF;
        acc += dis[s] * h[s * 32 + f];
    }
    float dd = dis[d];
    c[idx] = dd * acc + dd * dd * h[idx] + b[f];
}

// h2 (bf16) + kg copy into x0/xb0, one dispatch
__global__ void k_h2kg(const float* __restrict__ c1, const float* __restrict__ W,
                       const float* __restrict__ kg, unsigned short* __restrict__ h,
                       float* __restrict__ x0, unsigned short* __restrict__ xb0) {
    int idx = blockIdx.x * blockDim.x + threadIdx.x;
    if (idx >= N * 128) return;
    int n = idx >> 7, f = idx & 127;
    const float* cr = c1 + n * 32;
    float acc = 0.f;
    for (int c = 0; c < 32; ++c) acc += lrelu(cr[c], 0.01f) * W[c * 128 + f];
    h[idx] = f2bf(acc);
    float v = kg[idx];
    x0[n * 256 + f] = v;
    xb0[n * 256 + f] = f2bf(v);
}

__global__ void k_agg128(const int* __restrict__ rowptr, const int* __restrict__ csr_se,
                         const float* __restrict__ dis,
                         const unsigned short* __restrict__ h,
                         const float* __restrict__ b, float* __restrict__ x0,
                         unsigned short* __restrict__ xb0) {
    int idx = blockIdx.x * blockDim.x + threadIdx.x;
    if (idx >= N * 128) return;
    int d = idx >> 7, f = idx & 127;
    int beg = rowptr[d], end = rowptr[d + 1];
    float acc = 0.f;
    int i = beg;
    for (; i + 2 <= end; i += 2) {
        int s0 = csr_se[i] & 0xFFFF;
        int s1 = csr_se[i + 1] & 0xFFFF;
        float d0 = dis[s0], d1 = dis[s1];
        float v0 = bf2f(h[s0 * 128 + f]), v1 = bf2f(h[s1 * 128 + f]);
        acc += d0 * v0 + d1 * v1;
    }
    if (i < end) {
        int s = csr_se[i] & 0xFFFF;
        acc += dis[s] * bf2f(h[s * 128 + f]);
    }
    float dd = dis[d];
    float v = dd * acc + dd * dd * bf2f(h[d * 128 + f]) + b[f];
    x0[d * 256 + 128 + f] = v;
    xb0[d * 256 + 128 + f] = f2bf(v);
}

// ---------------- RGAT attention ----------------
// wave-per-(r,i) W@q / W@k projection: coalesced row read + shuffle reduce.
// wqkb[n][k]: n<32 -> q proj (n = r*4+h), n>=32 -> k proj (n = 32+r*4+h)
__global__ __launch_bounds__(256) void k_wqkb(const float* __restrict__ W,
                                              const float* __restrict__ q,
                                              const float* __restrict__ kmat,
                                              unsigned short* __restrict__ wqkb) {
    int w = (blockIdx.x * blockDim.x + threadIdx.x) >> 6;  // 0..2047
    int lane = threadIdx.x & 63;
    int r = w >> 8, i = w & 255;
    const float* wr = W + ((size_t)(r * 256 + i)) * 256;
    float4 a = *(const float4*)(wr + lane * 4);
    float aq0 = 0.f, aq1 = 0.f, aq2 = 0.f, aq3 = 0.f;
    float ak0 = 0.f, ak1 = 0.f, ak2 = 0.f, ak3 = 0.f;
    int o = lane * 4;
    const float av[4] = {a.x, a.y, a.z, a.w};
#pragma unroll
    for (int j = 0; j < 4; ++j) {
        float4 qv = *(const float4*)(q + (o + j) * 4);
        float4 kv = *(const float4*)(kmat + (o + j) * 4);
        aq0 += av[j] * qv.x; aq1 += av[j] * qv.y;
        aq2 += av[j] * qv.z; aq3 += av[j] * qv.w;
        ak0 += av[j] * kv.x; ak1 += av[j] * kv.y;
        ak2 += av[j] * kv.z; ak3 += av[j] * kv.w;
    }
#pragma unroll
    for (int d = 1; d < 64; d <<= 1) {
        aq0 += __shfl_xor(aq0, d); aq1 += __shfl_xor(aq1, d);
        aq2 += __shfl_xor(aq2, d); aq3 += __shfl_xor(aq3, d);
        ak0 += __shfl_xor(ak0, d); ak1 += __shfl_xor(ak1, d);
        ak2 += __shfl_xor(ak2, d); ak3 += __shfl_xor(ak3, d);
    }
    if (lane == 0) {
        int nq = r * 4, nk = 32 + r * 4;
        wqkb[(nq + 0) * 256 + i] = f2bf(aq0);
        wqkb[(nq + 1) * 256 + i] = f2bf(aq1);
        wqkb[(nq + 2) * 256 + i] = f2bf(aq2);
        wqkb[(nq + 3) * 256 + i] = f2bf(aq3);
        wqkb[(nk + 0) * 256 + i] = f2bf(ak0);
        wqkb[(nk + 1) * 256 + i] = f2bf(ak1);
        wqkb[(nk + 2) * 256 + i] = f2bf(ak2);
        wqkb[(nk + 3) * 256 + i] = f2bf(ak3);
    }
}

// qn|kn = xb @ wqkb^T via MFMA.  Block: 256 thr = 4 waves, 64 rows per block.
// Operands SWAPPED (mfma(b,a,acc) computes C^T): D-row = output col (kq*4+reg),
// D-col = node row (lrow) -> each lane holds 4 consecutive cols of one node row
// -> float4 stores.
#define QP 264
__global__ __launch_bounds__(256) void k_qnkn_mfma(
    const unsigned short* __restrict__ xb, const unsigned short* __restrict__ wqkb,
    float* __restrict__ qn, float* __restrict__ kn)
{
    __shared__ unsigned short Ws[64 * QP];
    int t = threadIdx.x;
    {
        int r = t >> 2, off = (t & 3) * 64;
#pragma unroll
        for (int i = 0; i < 8; ++i)
            *(uint4*)(&Ws[r * QP + off + i * 8]) =
                *(const uint4*)(wqkb + r * 256 + off + i * 8);
    }
    __syncthreads();
    int wave = t >> 6, lane = t & 63;
    int lrow = lane & 15, kq = lane >> 4;
    int mw = blockIdx.x * 64 + wave * 16;
    int gm = mw + lrow;
    int gmc = gm < N ? gm : N - 1;

    f32x4 acc[4];
#pragma unroll
    for (int j = 0; j < 4; ++j) acc[j] = (f32x4){0.f, 0.f, 0.f, 0.f};

    for (int k0 = 0; k0 < 8; ++k0) {
        short8 af = *(const short8*)(xb + (size_t)gmc * 256 + k0 * 32 + kq * 8);
#pragma unroll
        for (int j = 0; j < 4; ++j) {
            short8 bf4 = *(const short8*)(&Ws[(j * 16 + lrow) * QP + k0 * 32 + kq * 8]);
            acc[j] = __builtin_amdgcn_mfma_f32_16x16x32_bf16(bf4, af, acc[j], 0, 0, 0);
        }
    }
    if (gm < N) {
#pragma unroll
        for (int j = 0; j < 4; ++j) {
            int colb = j * 16 + kq * 4;
            float4 v = {acc[j][0], acc[j][1], acc[j][2], acc[j][3]};
            if (colb < 32) *(float4*)(qn + (size_t)gm * 32 + colb) = v;
            else           *(float4*)(kn + (size_t)gm * 32 + (colb - 32)) = v;
        }
    }
}

// wave-per-node softmax: lanes = 16 edge-slots x 4 heads, shuffle reductions.
__global__ void k_soft(const int* __restrict__ rowptr, const int* __restrict__ csr_se,
                       const int* __restrict__ csr_eid,
                       const float* __restrict__ qn, const float* __restrict__ kn,
                       float* __restrict__ alpha_csr, float* __restrict__ aout) {
    int wid = (blockIdx.x * blockDim.x + threadIdx.x) >> 6;
    int lane = threadIdx.x & 63;
    if (wid >= N) return;
    int d = wid;
    int beg = rowptr[d], end = rowptr[d + 1];
    if (beg >= end) return;
    int slot = lane >> 2, h = lane & 3;
    int nc = (end - beg + 15) >> 4;
    const float* qrow = qn + d * 32;

    auto rawv = [&](int i) {
        int se = csr_se[i];
        int tt = se >> 16, s = se & 0xFFFF;
        return lrelu(qrow[tt * 4 + h] + kn[s * 32 + tt * 4 + h], 0.2f);
    };

    float av[4];
    float m = -1e30f;
    for (int c = 0; c < nc; ++c) {
        int i = beg + c * 16 + slot;
        float v = (i < end) ? rawv(i) : -1e30f;
        if (c < 4) av[c] = v;
        m = fmaxf(m, v);
    }
    m = fmaxf(m, __shfl_xor(m, 4));
    m = fmaxf(m, __shfl_xor(m, 8));
    m = fmaxf(m, __shfl_xor(m, 16));
    m = fmaxf(m, __shfl_xor(m, 32));

    float sum = 0.f;
    for (int c = 0; c < nc; ++c) {
        int i = beg + c * 16 + slot;
        float ex = 0.f;
        if (i < end) {
            float v = (c < 4) ? av[c] : rawv(i);
            ex = expf(v - m);
        }
        if (c < 4) av[c] = ex;
        sum += ex;
    }
    sum += __shfl_xor(sum, 4);
    sum += __shfl_xor(sum, 8);
    sum += __shfl_xor(sum, 16);
    sum += __shfl_xor(sum, 32);
    float inv = 1.f / sum;

    for (int c = 0; c < nc; ++c) {
        int i = beg + c * 16 + slot;
        if (i < end) {
            float ex = (c < 4) ? av[c] : expf(rawv(i) - m);
            float a = ex * inv;
            alpha_csr[i * 4 + h] = a;
            aout[csr_eid[i] * 4 + h] = a;
        }
    }
}

// Wt[z][n][k] = bf16(W[z][k][n])  -- 64x64 LDS-tile transpose, coalesced both ways
#define WTP 72
__global__ __launch_bounds__(256) void k_wconv_t(const float* __restrict__ W,
                                                 unsigned short* __restrict__ Wt) {
    int bid = blockIdx.x;
    int z = bid >> 4;
    int tile = bid & 15;
    int k0 = (tile >> 2) * 64, n0 = (tile & 3) * 64;
    __shared__ unsigned short T[64 * WTP];
    int t = threadIdx.x;
    const float* Wz = W + ((size_t)z << 16);
    int r = t >> 4;
    int cs = (t & 15) * 4;
#pragma unroll
    for (int rr = 0; rr < 4; ++rr) {
        int k = r + rr * 16;
        float4 v = *(const float4*)(Wz + (size_t)(k0 + k) * 256 + n0 + cs);
        T[(cs + 0) * WTP + k] = f2bf(v.x);
        T[(cs + 1) * WTP + k] = f2bf(v.y);
        T[(cs + 2) * WTP + k] = f2bf(v.z);
        T[(cs + 3) * WTP + k] = f2bf(v.w);
    }
    __syncthreads();
    int n = t >> 2, ck = (t & 3) * 16;
    unsigned short* dst = Wt + ((size_t)z << 16) + (size_t)(n0 + n) * 256 + k0 + ck;
    const unsigned short* srcp = T + n * WTP + ck;
    *(uint4*)(dst) = *(const uint4*)(srcp);
    *(uint4*)(dst + 8) = *(const uint4*)(srcp + 8);
}

// ---------------- bf16 MFMA GEMM: m97 structure + swizzle + C^T epilogue -------
// M-SPLIT: MTd tiles starting at tile mt0 (keeps top-5 visibility of non-gemms)
#define TM 128
#define TN 128
__global__ __launch_bounds__(256) void gemm_mfma4(
    const unsigned short* __restrict__ A, const unsigned short* __restrict__ Bt,
    unsigned short* __restrict__ Cbf, float* __restrict__ Cf,
    const float* __restrict__ bias, const float* __restrict__ bias2,
    int M, int NZ, int NT, int MTd, int mt0, int zlin)
{
    __shared__ unsigned short As[128 * 32];
    __shared__ unsigned short Bs[128 * 32];

    int bi = blockIdx.x;
    int cx = bi & 7;
    int g = bi >> 3;
    int per = NZ * NT;
    int mh = g / per;
    int j  = g % per;
    int mtl = mh * 8 + cx;
    if (mtl >= MTd) return;
    int mt = mt0 + mtl;
    int z  = j % NZ;
    int nb = j / NZ;
    int m0 = mt * TM;
    int n0 = nb * TN;

    const unsigned short* Bz = Bt + ((size_t)z << 16);
    int t = threadIdx.x;
    int wave = t >> 6, lane = t & 63;
    int wr = wave >> 1, wc = wave & 1;
    int lrow = lane & 15, kq = lane >> 4;

    // staging: source col-group pre-swizzled: LDS[row][gp]=global[row][gp^((row>>1)&3)]
    int sr0 = (wave * 2 + 0) * 16 + (lane >> 2);
    int sr1 = (wave * 2 + 1) * 16 + (lane >> 2);
    int sc = (((lane & 3) ^ ((lane >> 3) & 3))) * 8;
    int gm0 = m0 + sr0; if (gm0 >= M) gm0 = M - 1;  // clamp: dup rows never stored
    int gm1 = m0 + sr1; if (gm1 >= M) gm1 = M - 1;
    const unsigned short* gA0 = A + (size_t)gm0 * 256 + sc;
    const unsigned short* gA1 = A + (size_t)gm1 * 256 + sc;
    const unsigned short* gB0 = Bz + (size_t)(n0 + sr0) * 256 + sc;
    const unsigned short* gB1 = Bz + (size_t)(n0 + sr1) * 256 + sc;
    unsigned short* lA0 = &As[(wave * 2 + 0) * 512];
    unsigned short* lA1 = &As[(wave * 2 + 1) * 512];
    unsigned short* lB0 = &Bs[(wave * 2 + 0) * 512];
    unsigned short* lB1 = &Bs[(wave * 2 + 1) * 512];

    // read-side swizzled K-group offset (elements)
    int rg = (kq ^ ((lrow >> 1) & 3)) * 8;

    f32x4 acc[4][4];
#pragma unroll
    for (int i = 0; i < 4; ++i)
#pragma unroll
        for (int jj = 0; jj < 4; ++jj) acc[i][jj] = (f32x4){0.f, 0.f, 0.f, 0.f};

    for (int k0 = 0; k0 < 256; k0 += 32) {
        gl2l16(gA0 + k0, lA0);
        gl2l16(gA1 + k0, lA1);
        gl2l16(gB0 + k0, lB0);
        gl2l16(gB1 + k0, lB1);
        __syncthreads();   // drains vmcnt(0) before barrier
        short8 af[4], bf4[4];
#pragma unroll
        for (int i = 0; i < 4; ++i)
            af[i] = *(const short8*)(&As[(wr * 64 + i * 16 + lrow) * 32 + rg]);
#pragma unroll
        for (int jj = 0; jj < 4; ++jj)
            bf4[jj] = *(const short8*)(&Bs[(wc * 64 + jj * 16 + lrow) * 32 + rg]);
#pragma unroll
        for (int i = 0; i < 4; ++i)
#pragma unroll
            for (int jj = 0; jj < 4; ++jj)
                acc[i][jj] = __builtin_amdgcn_mfma_f32_16x16x32_bf16(bf4[jj], af[i],
                                                                     acc[i][jj], 0, 0, 0);
        __syncthreads();
    }
    // transposed D: each lane -> row gm = m0+wr*64+i*16+lrow,
    //               cols gnb..gnb+3 = n0+wc*64+jj*16+kq*4 ..
    if (z == zlin) {
#pragma unroll
        for (int i = 0; i < 4; ++i) {
            int gm = m0 + wr * 64 + i * 16 + lrow;
            if (gm >= M) continue;
#pragma unroll
            for (int jj = 0; jj < 4; ++jj) {
                int gnb = n0 + wc * 64 + jj * 16 + kq * 4;
                float4 b1 = *(const float4*)(bias + gnb);
                float4 b2 = *(const float4*)(bias2 + gnb);
                float4 v = {acc[i][jj][0] + b1.x + b2.x,
                            acc[i][jj][1] + b1.y + b2.y,
                            acc[i][jj][2] + b1.z + b2.z,
                            acc[i][jj][3] + b1.w + b2.w};
                *(float4*)(Cf + (size_t)gm * 256 + gnb) = v;
            }
        }
    } else {
#pragma unroll
        for (int i = 0; i < 4; ++i) {
            int gm = m0 + wr * 64 + i * 16 + lrow;
            if (gm >= M) continue;
#pragma unroll
            for (int jj = 0; jj < 4; ++jj) {
                int gnb = n0 + wc * 64 + jj * 16 + kq * 4;
                us4 v = {f2bf(acc[i][jj][0]), f2bf(acc[i][jj][1]),
                         f2bf(acc[i][jj][2]), f2bf(acc[i][jj][3])};
                *(us4*)(Cbf + ((size_t)z * M + gm) * 256 + gnb) = v;
            }
        }
    }
}

// ---------------- message aggregation: 1 wave per node, 4-deep edge pipeline ---
__global__ __launch_bounds__(256) void k_msg_gather(
    const int* __restrict__ rowptr, const int* __restrict__ csr_se,
    const float* __restrict__ alpha_csr, const unsigned short* __restrict__ xw,
    const float* __restrict__ bias, float* __restrict__ out,
    unsigned short* __restrict__ xbout, int r0, int r1, int first, int act) {
    int node = blockIdx.x * 4 + (threadIdx.x >> 6);
    if (node >= N) return;
    int lane = threadIdx.x & 63;
    int hsel = lane >> 4;
    int beg = rowptr[node], end = rowptr[node + 1];
    float ax = 0.f, ay = 0.f, az = 0.f, aw = 0.f;
    const unsigned short* xwl = xw + lane * 4;

    auto accum = [&](int se, float a) {
        int tt = se >> 16, s = se & 0xFFFF;
        uint2 pv = *(const uint2*)(xwl + ((size_t)tt * N + s) * 256);
        ax += a * __uint_as_float(pv.x << 16);
        ay += a * __uint_as_float(pv.x & 0xFFFF0000u);
        az += a * __uint_as_float(pv.y << 16);
        aw += a * __uint_as_float(pv.y & 0xFFFF0000u);
    };

    if (r0 == 0 && r1 == R) {
        int i = beg;
        for (; i + 4 <= end; i += 4) {
            int se0 = csr_se[i], se1 = csr_se[i + 1];
            int se2 = csr_se[i + 2], se3 = csr_se[i + 3];
            float a0 = alpha_csr[i * 4 + hsel];
            float a1 = alpha_csr[i * 4 + 4 + hsel];
            float a2 = alpha_csr[i * 4 + 8 + hsel];
            float a3 = alpha_csr[i * 4 + 12 + hsel];
            accum(se0, a0); accum(se1, a1); accum(se2, a2); accum(se3, a3);
        }
        for (; i < end; ++i) accum(csr_se[i], alpha_csr[i * 4 + hsel]);
    } else {
        for (int i = beg; i < end; ++i) {
            int se = csr_se[i];
            int tt = se >> 16;
            if (tt >= r0 && tt < r1) {
                int s = se & 0xFFFF;
                float a = alpha_csr[i * 4 + hsel];
                uint2 pv = *(const uint2*)(xwl + ((size_t)(tt - r0) * N + s) * 256);
                ax += a * __uint_as_float(pv.x << 16);
                ay += a * __uint_as_float(pv.x & 0xFFFF0000u);
                az += a * __uint_as_float(pv.y << 16);
                aw += a * __uint_as_float(pv.y & 0xFFFF0000u);
            }
        }
    }

    float* o = out + (size_t)node * 256 + lane * 4;
    float vx, vy, vz, vw;
    if (first) {
        float4 b = *(const float4*)(bias + lane * 4);
        vx = ax + b.x; vy = ay + b.y; vz = az + b.z; vw = aw + b.w;
    } else {
        float4 q = *(const float4*)o;
        vx = q.x + ax; vy = q.y + ay; vz = q.z + az; vw = q.w + aw;
    }
    if (act) {
        vx = lrelu(vx, 0.01f); vy = lrelu(vy, 0.01f);
        vz = lrelu(vz, 0.01f); vw = lrelu(vw, 0.01f);
        us4 xv = {f2bf(vx), f2bf(vy), f2bf(vz), f2bf(vw)};
        *(us4*)(xbout + (size_t)node * 256 + lane * 4) = xv;
    }
    float4 v = {vx, vy, vz, vw};
    *(float4*)o = v;
}

extern "C" void kernel_launch(void* const* d_in, const int* in_sizes, int n_in,
                              void* d_out, int out_size, void* d_ws, size_t ws_size,
                              hipStream_t stream) {
    const float* kg   = (const float*)d_in[0];
    const float* cc0  = (const float*)d_in[1];
    const float* gw1  = (const float*)d_in[2];
    const float* gb1  = (const float*)d_in[3];
    const float* gw2  = (const float*)d_in[4];
    const float* gb2  = (const float*)d_in[5];
    const float* r1w  = (const float*)d_in[6];
    const float* r1q  = (const float*)d_in[7];
    const float* r1k  = (const float*)d_in[8];
    const float* r1b  = (const float*)d_in[9];
    const float* r2w  = (const float*)d_in[10];
    const float* r2q  = (const float*)d_in[11];
    const float* r2k  = (const float*)d_in[12];
    const float* r2b  = (const float*)d_in[13];
    const float* linw = (const float*)d_in[14];
    const float* linb = (const float*)d_in[15];
    const int*   ei   = (const int*)d_in[16];
    const int*   et   = (const int*)d_in[17];

    float* out = (float*)d_out;
    float* a1  = out + (size_t)N * C;
    float* a2  = a1 + (size_t)E * H;

    float* ws = (float*)d_ws;
    size_t off = 0;
    float* dis  = ws + off; off += N;
    float* h1   = ws + off; off += (size_t)N * 32;
    float* c1   = ws + off; off += (size_t)N * 32;
    unsigned short* h2b = (unsigned short*)(ws + off); off += (size_t)N * 64;
    float* x0   = ws + off; off += (size_t)N * C;
    float* hmid = ws + off; off += (size_t)N * C;
    float* qn   = ws + off; off += (size_t)N * R * H;
    float* kn   = ws + off; off += (size_t)N * R * H;
    int* cnt     = (int*)(ws + off); off += N;
    int* rowptr  = (int*)(ws + off); off += N + 1;
    int* cursor  = (int*)(ws + off); off += N;
    int* scanloc = (int*)(ws + off); off += N;
    int* scanbs  = (int*)(ws + off); off += 256;
    int* csr_se  = (int*)(ws + off); off += E;
    int* csr_eid = (int*)(ws + off); off += E;
    float* alpha = ws + off; off += (size_t)E * H;
    unsigned short* xb0 = (unsigned short*)(ws + off); off += (size_t)N * 128;
    unsigned short* xb1 = (unsigned short*)(ws + off); off += (size_t)N * 128;
    // wt[0..R-1] = RGAT weights (transposed bf16); wt[R] = lin weight -> contiguous
    unsigned short* wt  = (unsigned short*)(ws + off); off += (size_t)(R + 1) * 32768;
    unsigned short* wtl = wt + ((size_t)R << 16);
    unsigned short* wqkb = (unsigned short*)(ws + off); off += 8192;
    unsigned short* xwb = (unsigned short*)(ws + off);

    size_t fixedB = off * 4;
    int K = R;
    if (ws_size > fixedB) {
        size_t kmax = (ws_size - fixedB) / ((size_t)N * C * 2);
        if (kmax < (size_t)K) K = (int)kmax;
    } else {
        K = 1;
    }
    if (K < 1) K = 1;

    const int B = 256;
    auto cdiv = [](long a, long b) { return (int)((a + b - 1) / b); };
    const int MT = cdiv(N, TM);  // 157 m-tiles
    const int NT = C / TN;       // 2
    const int mtA = (MT + 1) / 2;    // 79
    const int mtB = MT - mtA;        // 78
    const int NB = cdiv(N, 256);     // 79 scan blocks

    // ---- CSR build ----
    k_zero_int<<<cdiv(N, B), B, 0, stream>>>(cnt, N);
    k_count<<<cdiv(E, B), B, 0, stream>>>(ei, cnt);
    k_scan_a<<<NB, 256, 0, stream>>>(cnt, scanloc, scanbs);
    k_scan_b<<<1, 256, 0, stream>>>(scanbs, NB);
    k_scan_c<<<NB, 256, 0, stream>>>(cnt, scanloc, scanbs, rowptr, cursor, dis);
    k_scatter<<<cdiv(E, B), B, 0, stream>>>(ei, et, cursor, csr_se, csr_eid);

    // ---- GCN ----
    k_h1<<<cdiv((long)N * 32, B), B, 0, stream>>>(cc0, gw1, h1);
    k_agg32<<<cdiv((long)N * 32, B), B, 0, stream>>>(rowptr, csr_se, dis, h1, gb1, c1);
    k_h2kg<<<cdiv((long)N * 128, B), B, 0, stream>>>(c1, gw2, kg, h2b, x0, xb0);
    k_agg128<<<cdiv((long)N * 128, B), B, 0, stream>>>(rowptr, csr_se, dis, h2b,
                                                       gb2, x0, xb0);

    auto rgat = [&](unsigned short* xb, const float* W,
                    const float* q, const float* kk, const float* b,
                    float* obuf, unsigned short* xbout, float* aout,
                    int first, int act, int lin, float* linout,
                    const float* lb1, const float* lb2) {
        k_wqkb<<<512, 256, 0, stream>>>(W, q, kk, wqkb);
        k_qnkn_mfma<<<cdiv(N, 64), B, 0, stream>>>(xb, wqkb, qn, kn);
        k_soft<<<cdiv((long)N * 64, B), B, 0, stream>>>(rowptr, csr_se, csr_eid,
                                                        qn, kn, alpha, aout);
        k_wconv_t<<<R * 16, 256, 0, stream>>>(W, wt);
        for (int r0 = 0; r0 < R; r0 += K) {
            int kc = (R - r0) < K ? (R - r0) : K;
            int addlin = (lin && (r0 + kc == R)) ? 1 : 0;
            int nz = kc + addlin;
            int zl = addlin ? kc : -1;
            int gx1 = 8 * nz * NT * cdiv(mtA, 8);
            gemm_mfma4<<<gx1, 256, 0, stream>>>(xb, wt + ((size_t)r0 << 16), xwb,
                                                linout, lb1, lb2,
                                                N, nz, NT, mtA, 0, zl);
            int gx2 = 8 * nz * NT * cdiv(mtB, 8);
            gemm_mfma4<<<gx2, 256, 0, stream>>>(xb, wt + ((size_t)r0 << 16), xwb,
                                                linout, lb1, lb2,
                                                N, nz, NT, mtB, mtA, zl);
            int last = (r0 + kc >= R) ? 1 : 0;
            k_msg_gather<<<cdiv(N, 4), 256, 0, stream>>>(
                rowptr, csr_se, alpha, xwb, b, obuf, xbout, r0, r0 + kc,
                (first && r0 == 0) ? 1 : 0, act && last);
        }
    };

    // residual-linear weight transposed into wt[R] before layer 1
    k_wconv_t<<<16, 256, 0, stream>>>(linw, wtl);

    // layer 1: hmid = r1b + messages (leaky fused, emits xb1 bf16);
    //          merged z=8 slice writes out = x0@linw + (linb + r2b)
    rgat(xb0, r1w, r1q, r1k, r1b, hmid, xb1, a1, 1, 1,
         1, out, linb, r2b);

    // layer 2: out += messages (bias already folded into linear epilogue)
    rgat(xb1, r2w, r2q, r2k, r2b, out, nullptr, a2, 0, 0,
         0, nullptr, nullptr, nullptr);
}